// Round 10
// baseline (782.442 us; speedup 1.0000x reference)
//
#include <hip/hip_runtime.h>
#include <math.h>

namespace {
constexpr int BN = 64;
constexpr int HW = 1024;
constexpr int NS = BN*8*HW;      // 524288

constexpr float C2f = 0.2f, C3f = 0.3f, C4f = 0.8f, C5f = (float)(8.0/9.0);
constexpr float A21 = 0.2f;
constexpr float A31 = (float)(3.0/40.0),  A32 = (float)(9.0/40.0);
constexpr float A41 = (float)(44.0/45.0), A42 = (float)(-56.0/15.0), A43 = (float)(32.0/9.0);
constexpr float A51 = (float)(19372.0/6561.0), A52 = (float)(-25360.0/2187.0),
                A53 = (float)(64448.0/6561.0), A54 = (float)(-212.0/729.0);
constexpr float A61 = (float)(9017.0/3168.0), A62 = (float)(-355.0/33.0),
                A63 = (float)(46732.0/5247.0), A64 = (float)(49.0/176.0),
                A65 = (float)(-5103.0/18656.0);
constexpr float B1c = (float)(35.0/384.0), B3c = (float)(500.0/1113.0),
                B4c = (float)(125.0/192.0), B5c = (float)(-2187.0/6784.0),
                B6c = (float)(11.0/84.0);
constexpr float E1c = (float)(71.0/57600.0), E3c = (float)(-71.0/16695.0),
                E4c = (float)(71.0/1920.0), E5c = (float)(-17253.0/339200.0),
                E6c = (float)(22.0/525.0),  E7c = (float)(-1.0/40.0);
constexpr float RTOL = 1e-3f, ATOL = 1e-3f;

// ws layout (floats / ints)
constexpr size_t OFF_PART = 0;        // 1024 floats (double-buffered by step parity)
constexpr size_t OFF_FLAG = 1024;     // 512 ints (tile fully done; step gate)
constexpr size_t OFF_CNT  = 1536;     // unused, kept
constexpr size_t OFF_TSUM = 1600;     // 576
constexpr size_t OFF_W2P  = 2176;     // 36864 halfs = 18432 floats
constexpr size_t OFF_Y    = 20608;    // y buffers px-major: [b][px][8]
constexpr size_t OFF_Y5   = OFF_Y  + (size_t)NS;
constexpr size_t OFF_K    = OFF_Y5 + (size_t)NS;   // 7*NS (k1..k7, px-major)
constexpr size_t OFF_WPK  = OFF_K + (size_t)7*NS;  // w1t(512) w10(64) w3t(512) w30(8)
constexpr size_t OFF_FT   = OFF_WPK + 1152;        // 512 ints: top-row ready
constexpr size_t OFF_FB   = OFF_FT + 512;          // 512 ints: bottom-row ready

// LDS strides (bytes), both == 4 dwords (mod 32): b128 ops tile banks (R0-style).
constexpr int ACT_STRIDE = 272;   // 192 px rows (6x32), 128B payload
constexpr int H2_STRIDE  = 144;   // 128 px rows, 128B payload
}

__constant__ float g_cf[6][5] = {
    {A21, 0, 0, 0, 0},
    {A31, A32, 0, 0, 0},
    {A41, A42, A43, 0, 0},
    {A51, A52, A53, A54, 0},
    {A61, A62, A63, A64, A65},
    {0, 0, 0, 0, 0}};
__constant__ float g_ct[6] = {C2f, C3f, C4f, C5f, 1.0f, 1.0f};

typedef _Float16 hfrag8 __attribute__((ext_vector_type(8)));
typedef float f32x16 __attribute__((ext_vector_type(16)));

union HU { hfrag8 h; unsigned u[4]; uint4 v; };

// ---- system-scope (L3-coherent) accessors ----
__device__ __forceinline__ float ld_sysf(const float* p) {
    return __hip_atomic_load(p, __ATOMIC_RELAXED, __HIP_MEMORY_SCOPE_SYSTEM);
}
__device__ __forceinline__ float2 ld_sysf2(const float* p) {
    union { unsigned long long u; float2 f; } c;
    c.u = __hip_atomic_load((const unsigned long long*)p, __ATOMIC_RELAXED,
                            __HIP_MEMORY_SCOPE_SYSTEM);
    return c.f;
}
__device__ __forceinline__ void st_sysf(float* p, float v) {
    __hip_atomic_store(p, v, __ATOMIC_RELAXED, __HIP_MEMORY_SCOPE_SYSTEM);
}
__device__ __forceinline__ void st_sysf2(float* p, float a, float b) {
    union { unsigned long long u; float2 f; } c;
    c.f = make_float2(a, b);
    __hip_atomic_store((unsigned long long*)p, c.u, __ATOMIC_RELAXED,
                       __HIP_MEMORY_SCOPE_SYSTEM);
}

// 8-float load/store; sys = NEIGHBOR-written (L3) vs self-written (L2 plain)
__device__ __forceinline__ void ld8(const float* p, float* v, bool sys) {
    if (sys) {
        #pragma unroll
        for (int h = 0; h < 4; h++) {
            float2 t = ld_sysf2(p + 2*h);
            v[2*h] = t.x; v[2*h+1] = t.y;
        }
    } else {
        float4 a = *(const float4*)p;
        float4 b = *(const float4*)(p + 4);
        v[0]=a.x; v[1]=a.y; v[2]=a.z; v[3]=a.w;
        v[4]=b.x; v[5]=b.y; v[6]=b.z; v[7]=b.w;
    }
}
__device__ __forceinline__ void st8(float* p, const float* v, bool sys) {
    if (sys) {
        st_sysf2(p,     v[0], v[1]);
        st_sysf2(p + 2, v[2], v[3]);
        st_sysf2(p + 4, v[4], v[5]);
        st_sysf2(p + 6, v[6], v[7]);
    } else {
        *(float4*)p       = make_float4(v[0], v[1], v[2], v[3]);
        *(float4*)(p + 4) = make_float4(v[4], v[5], v[6], v[7]);
    }
}

// ---------------- init ----------------
__global__ __launch_bounds__(256)
void k_init(const float* __restrict__ x, float* __restrict__ y,
            int* __restrict__ flags, int* __restrict__ flagT,
            int* __restrict__ flagB)
{
    int idx = blockIdx.x*256 + threadIdx.x;           // < NS
    int b = idx >> 13, px = (idx >> 3) & 1023, c = idx & 7;
    y[idx] = (c < 3) ? x[(size_t)(b*3 + c)*1024 + px] : 0.0f;
    if (idx < 512) { flags[idx] = 0; flagT[idx] = 0; flagB[idx] = 0; }
}

// ---------------- prepack ----------------
__global__ __launch_bounds__(256)
void k_prepack(const float* __restrict__ w1, const float* __restrict__ w2,
               const float* __restrict__ w3, _Float16* __restrict__ w2p,
               float* __restrict__ tsum, float* __restrict__ wpk)
{
    int gid = blockIdx.x*256 + threadIdx.x;
    if (gid < 36864) {
        int j    = gid & 7;
        int lane = (gid >> 3) & 63;
        int nt   = (gid >> 9) & 1;
        int ks   = (gid >> 10) & 3;
        int tap  = gid >> 12;            // 0..8
        int oc = nt*32 + (lane & 31);
        int kpos = ks*16 + (lane >> 5)*8 + j;
        int oct = kpos >> 5, q2b = (kpos >> 4) & 1, rr = kpos & 15;
        int ic = oct*32 + (rr & 3) + (q2b << 2) + ((rr >> 2) << 3);  // inv-pi
        w2p[gid] = (_Float16)w2[oc*585 + (1 + ic)*9 + tap];
    }
    if (gid < 576) {
        int oc = gid & 63, combo = gid >> 6;       // 0..8
        int rcase = combo / 3, ccase = combo % 3;
        float s = 0.0f;
        for (int kh = 0; kh < 3; kh++) {
            if ((rcase == 1 && kh == 0) || (rcase == 2 && kh == 2)) continue;
            for (int kw = 0; kw < 3; kw++) {
                if ((ccase == 1 && kw == 0) || (ccase == 2 && kw == 2)) continue;
                s += w2[oc*585 + kh*3 + kw];
            }
        }
        tsum[gid] = s;
    }
    if (gid < 512) wpk[gid] = w1[(gid & 63)*9 + 1 + (gid >> 6)];
    if (gid < 64)  wpk[512 + gid] = w1[gid*9];
    if (gid < 512) wpk[576 + gid] = w3[(gid & 7)*65 + 1 + (gid >> 3)];
    if (gid < 8)   wpk[1088 + gid] = w3[gid*65];
}

// ---------------- the whole ODE solve ----------------
// R10 = R6 base (best measured, 256us) + ONE surgical change: conv2
// accumulator split by K-half (acc2[ri][ks>>1]) -> 4 independent MFMA
// chains of 18 instead of 2 chains of 36. Conv2 goes latency-bound ->
// issue-bound. +32 VGPR (116->~150), no state held across MFMA regions.
__global__ void __launch_bounds__(256, 2)
k_ode(const float* __restrict__ b1, const float* __restrict__ b2,
      const float* __restrict__ b3, const _Float16* __restrict__ w2p,
      const float* __restrict__ tsumg, const float* __restrict__ wpk,
      const float* __restrict__ wl, const float* __restrict__ bl,
      float* __restrict__ ybuf, float* __restrict__ y5buf,
      float* __restrict__ kb, float* __restrict__ part,
      int* __restrict__ flags, int* __restrict__ flagT,
      int* __restrict__ flagB, float* __restrict__ out)
{
    __shared__ __align__(16) unsigned char s_pool[192*ACT_STRIDE]; // 52224
    __shared__ __align__(16) unsigned char s_h2[128*H2_STRIDE];    // 18432
    __shared__ float s_tsum[576];
    __shared__ float s_b2v[64], s_b1v[64], s_w10v[64];
    __shared__ float s_w30v[8], s_b3v[8];
    __shared__ float s_red[8];

    const int tid = threadIdx.x;
    const int nblk = gridDim.x;
    const int lane = tid & 63;
    const int m32 = lane & 31, q2 = lane >> 5;
    const int rp = tid >> 7;          // row-pair for conv2
    const int np = (tid >> 6) & 1;    // oc-half for conv2
    const int wid = tid >> 6;         // wave id
    const bool lz32 = (lane == 32);
    const bool lz31 = (lane == 31);

    if (tid < 64) {
        s_b2v[tid] = b2[tid];
        s_b1v[tid] = b1[tid];
        s_w10v[tid] = wpk[512 + tid];
    }
    if (tid < 8) { s_w30v[tid] = wpk[1088 + tid]; s_b3v[tid] = b3[tid]; }
    for (int i = tid; i < 576; i += 256) s_tsum[i] = tsumg[i];
    __syncthreads();

    // resident conv1 A-frags: lo (k=0..7 live) and hi (k=8..15 live)
    hfrag8 w1lo[2], w1hi[2];
    #pragma unroll
    for (int oct = 0; oct < 2; oct++)
        #pragma unroll
        for (int j = 0; j < 8; j++) {
            _Float16 wv = (_Float16)wpk[j*64 + oct*32 + m32];
            w1lo[oct][j] = q2 ? (_Float16)0.0f : wv;
            w1hi[oct][j] = q2 ? wv : (_Float16)0.0f;
        }
    // resident conv3 A-frags (channel positions permuted by inv-pi)
    hfrag8 w3f[4];
    #pragma unroll
    for (int kst = 0; kst < 4; kst++)
        #pragma unroll
        for (int j = 0; j < 8; j++) {
            int kpos = kst*16 + q2*8 + j;
            int oct = kpos >> 5, q2b = (kpos >> 4) & 1, rr = kpos & 15;
            int ch = oct*32 + (rr & 3) + (q2b << 2) + ((rr >> 2) << 3);
            w3f[kst][j] = (m32 < 8) ? (_Float16)wpk[576 + ch*8 + m32]
                                    : (_Float16)0.0f;
        }

    float t = 0.0f, dt = 0.1f;
    float* ya = ybuf; float* yb = y5buf;
    float* ka = kb;  float* kg = kb + 6*(size_t)NS;

    auto wait_all = [&](int target) {
        for (;;) {
            bool ok = (__hip_atomic_load(&flags[tid], __ATOMIC_RELAXED,
                           __HIP_MEMORY_SCOPE_SYSTEM) >= target)
                   && (__hip_atomic_load(&flags[tid + 256], __ATOMIC_RELAXED,
                           __HIP_MEMORY_SCOPE_SYSTEM) >= target);
            if (__syncthreads_and((int)ok)) break;
            __builtin_amdgcn_s_sleep(2);
        }
    };

    auto eval = [&](const float* src, int nc, const float* cf, float ctv,
                    float* kout, int mode, int gev, float* partp) {
        float dtc = fminf(dt, 1.0f - t);
        float ts  = t + ctv*dtc;

        for (int tile = blockIdx.x; tile < 512; tile += nblk) {
            int b = tile >> 3, rg = tile & 7;

            // ---- z-combine (memory path) ----
            auto zload = [&](int lr) {
                HU pz; pz.v = make_uint4(0u,0u,0u,0u);
                int r = rg*4 - 1 + lr;
                if ((unsigned)lr < 6u && (unsigned)r < 32u) {
                    bool nbr = (lr == 0) | (lr == 5);   // neighbor-written only
                    int px = (r << 5) + m32;
                    size_t pb8 = ((size_t)(b << 10) + px) << 3;
                    float kv[5][8], sv[8];
                    if (nbr) {
                        #pragma unroll
                        for (int j = 0; j < 5; j++) if (j < nc) {
                            const float* kp = (j == 0 ? ka : kb + (size_t)j*NS) + pb8;
                            #pragma unroll
                            for (int h = 0; h < 4; h++) {
                                float2 t2 = ld_sysf2(kp + 2*h);
                                kv[j][2*h] = t2.x; kv[j][2*h+1] = t2.y;
                            }
                        }
                        #pragma unroll
                        for (int h = 0; h < 4; h++) {
                            float2 t2 = ld_sysf2(src + pb8 + 2*h);
                            sv[2*h] = t2.x; sv[2*h+1] = t2.y;
                        }
                    } else {
                        #pragma unroll
                        for (int j = 0; j < 5; j++) if (j < nc) {
                            const float* kp = (j == 0 ? ka : kb + (size_t)j*NS) + pb8;
                            float4 a4 = *(const float4*)kp;
                            float4 b4 = *(const float4*)(kp + 4);
                            kv[j][0]=a4.x; kv[j][1]=a4.y; kv[j][2]=a4.z; kv[j][3]=a4.w;
                            kv[j][4]=b4.x; kv[j][5]=b4.y; kv[j][6]=b4.z; kv[j][7]=b4.w;
                        }
                        float4 a4 = *(const float4*)(src + pb8);
                        float4 b4 = *(const float4*)(src + pb8 + 4);
                        sv[0]=a4.x; sv[1]=a4.y; sv[2]=a4.z; sv[3]=a4.w;
                        sv[4]=b4.x; sv[5]=b4.y; sv[6]=b4.z; sv[7]=b4.w;
                    }
                    float s_[8] = {0,0,0,0,0,0,0,0};
                    #pragma unroll
                    for (int j = 0; j < 5; j++) if (j < nc) {
                        float a = cf[j];
                        #pragma unroll
                        for (int c = 0; c < 8; c++) s_[c] = fmaf(a, kv[j][c], s_[c]);
                    }
                    #pragma unroll
                    for (int c = 0; c < 8; c++)
                        pz.h[c] = (_Float16)(sv[c] + dtc*s_[c]);
                }
                return pz;
            };

            HU pz;
            if (q2 == 0) pz = zload(wid + 1);      // own rows 1..4 (issued pre-spin)
            if (gev > 1 && q2 == 1 && (wid == 0 || wid == 3)) {
                bool need = (wid == 0) ? (rg > 0) : (rg < 7);
                if (need) {
                    const int* fp = (wid == 0) ? &flagB[tile-1] : &flagT[tile+1];
                    while (__hip_atomic_load(fp, __ATOMIC_RELAXED,
                                             __HIP_MEMORY_SCOPE_SYSTEM) < gev-1)
                        __builtin_amdgcn_s_sleep(1);
                }
            }
            if (q2 == 1) pz = zload((wid == 0) ? 0 : ((wid == 3) ? 5 : -1));

            // ---- conv1 via MFMA from registers; act write (pi-permuted) ----
            auto wr_act = [&](int lr, const f32x16& a1, int oct, bool valid) {
                unsigned words[8];
                #pragma unroll
                for (int pr = 0; pr < 8; pr++) {
                    int r0 = 2*pr;
                    int oc0 = oct*32 + (r0 & 3) + 8*(r0 >> 2) + 4*q2;
                    float v0 = valid ? fmaxf(a1[r0]   + ts*s_w10v[oc0]
                                             + s_b1v[oc0],   0.0f) : 0.0f;
                    float v1 = valid ? fmaxf(a1[r0+1] + ts*s_w10v[oc0+1]
                                             + s_b1v[oc0+1], 0.0f) : 0.0f;
                    union { _Float16 h[2]; unsigned u; } pk;
                    pk.h[0] = (_Float16)v0; pk.h[1] = (_Float16)v1;
                    words[pr] = pk.u;
                }
                unsigned char* basep = s_pool + (size_t)(lr*32 + m32)*ACT_STRIDE
                                       + oct*64 + q2*32;
                *(uint4*)basep        = make_uint4(words[0],words[1],words[2],words[3]);
                *(uint4*)(basep + 16) = make_uint4(words[4],words[5],words[6],words[7]);
            };
            {
                f32x16 zz = (f32x16)(0.0f);
                f32x16 c0 = __builtin_amdgcn_mfma_f32_32x32x16_f16(w1lo[0], pz.h, zz, 0,0,0);
                f32x16 c1 = __builtin_amdgcn_mfma_f32_32x32x16_f16(w1lo[1], pz.h, zz, 0,0,0);
                wr_act(wid + 1, c0, 0, true);
                wr_act(wid + 1, c1, 1, true);
                if (wid == 0 || wid == 3) {
                    int lrh = (wid == 0) ? 0 : 5;
                    bool vh = (unsigned)(rg*4 - 1 + lrh) < 32u;
                    f32x16 d0 = __builtin_amdgcn_mfma_f32_32x32x16_f16(w1hi[0], pz.h, zz, 0,0,0);
                    f32x16 d1 = __builtin_amdgcn_mfma_f32_32x32x16_f16(w1hi[1], pz.h, zz, 0,0,0);
                    wr_act(lrh, d0, 0, vh);
                    wr_act(lrh, d1, 1, vh);
                }
            }
            __syncthreads();   // BARRIER-A: act complete

            // ---- conv2: center b128 loads + DPP kw shifts; 4 indep chains ----
            f32x16 acc2[2][2];   // [ri][ks>>1]
            acc2[0][0] = (f32x16)(0.0f);
            acc2[0][1] = (f32x16)(0.0f);
            acc2[1][0] = (f32x16)(0.0f);
            acc2[1][1] = (f32x16)(0.0f);
            {
                const unsigned char* actb = (const unsigned char*)s_pool;
                #pragma unroll 1
                for (int ks = 0; ks < 4; ks++) {
                    int kh2 = ks >> 1;
                    HU fc[4], d0[4], d2[4];
                    #pragma unroll
                    for (int l = 0; l < 4; l++) {
                        const unsigned char* p = actb
                            + (size_t)((rp*2 + l)*32 + m32)*ACT_STRIDE
                            + ks*32 + q2*16;
                        fc[l].v = *(const uint4*)p;
                    }
                    #pragma unroll
                    for (int l = 0; l < 4; l++) {
                        #pragma unroll
                        for (int i = 0; i < 4; i++) {
                            unsigned s0 = (unsigned)__builtin_amdgcn_update_dpp(
                                0, (int)fc[l].u[i], 0x138, 0xF, 0xF, true); // wave_shr:1
                            d0[l].u[i] = lz32 ? 0u : s0;
                            unsigned s2 = (unsigned)__builtin_amdgcn_update_dpp(
                                0, (int)fc[l].u[i], 0x130, 0xF, 0xF, true); // wave_shl:1
                            d2[l].u[i] = lz31 ? 0u : s2;
                        }
                    }
                    #pragma unroll
                    for (int kh = 0; kh < 3; kh++) {
                        #pragma unroll
                        for (int kw = 0; kw < 3; kw++) {
                            int tap = kh*3 + kw;
                            hfrag8 aw = *(const hfrag8*)
                                (w2p + (size_t)((tap*4 + ks)*2 + np)*512 + lane*8);
                            #pragma unroll
                            for (int ri = 0; ri < 2; ri++) {
                                int l = ri + kh;
                                hfrag8 bf = (kw == 0) ? d0[l].h
                                          : ((kw == 1) ? fc[l].h : d2[l].h);
                                acc2[ri][kh2] = __builtin_amdgcn_mfma_f32_32x32x16_f16(
                                    aw, bf, acc2[ri][kh2], 0, 0, 0);
                            }
                        }
                    }
                }
            }

            // ---- conv2 epilogue -> h2 (pi-permuted px-major fp16) ----
            {
                int ccase = (m32 == 0) ? 1 : ((m32 == 31) ? 2 : 0);
                #pragma unroll
                for (int ri = 0; ri < 2; ri++) {
                    int pg = rp*2 + ri;
                    int r_out = rg*4 + pg;
                    int rcase = (r_out == 0) ? 1 : ((r_out == 31) ? 2 : 0);
                    const float* tsb = &s_tsum[(rcase*3 + ccase)*64];
                    int px = pg*32 + m32;
                    unsigned words[8];
                    #pragma unroll
                    for (int pr = 0; pr < 8; pr++) {
                        int r0 = 2*pr;
                        int oc0 = np*32 + (r0 & 3) + 8*(r0 >> 2) + 4*q2;
                        float a0 = acc2[ri][0][r0]   + acc2[ri][1][r0];
                        float a1 = acc2[ri][0][r0+1] + acc2[ri][1][r0+1];
                        float v0 = fmaxf(a0 + ts*tsb[oc0]   + s_b2v[oc0],   0.0f);
                        float v1 = fmaxf(a1 + ts*tsb[oc0+1] + s_b2v[oc0+1], 0.0f);
                        union { _Float16 h[2]; unsigned u; } pk;
                        pk.h[0] = (_Float16)v0; pk.h[1] = (_Float16)v1;
                        words[pr] = pk.u;
                    }
                    unsigned char* basep = s_h2 + (size_t)px*H2_STRIDE
                                           + np*64 + q2*32;
                    *(uint4*)basep        = make_uint4(words[0],words[1],words[2],words[3]);
                    *(uint4*)(basep + 16) = make_uint4(words[4],words[5],words[6],words[7]);
                }
            }
            __syncthreads();   // BARRIER-B: h2 complete

            // ---- conv3 via MFMA + mode epilogues ----
            float ls = 0.0f;
            {
                f32x16 a3a = (f32x16)(0.0f);
                #pragma unroll
                for (int kst = 0; kst < 4; kst++) {
                    HU f;
                    const unsigned char* p = s_h2
                        + (size_t)(wid*32 + m32)*H2_STRIDE + kst*32 + q2*16;
                    f.v = *(const uint4*)p;
                    a3a = __builtin_amdgcn_mfma_f32_32x32x16_f16(
                        w3f[kst], f.h, a3a, 0, 0, 0);
                }
                float a3[8];
                #pragma unroll
                for (int r = 0; r < 4; r++) {
                    float own = a3a[r];
                    float oth = __shfl(own, lane ^ 32, 64);
                    a3[r]     = q2 ? oth : own;
                    a3[4 + r] = q2 ? own : oth;
                }
                if (q2 == 0) {
                    #pragma unroll
                    for (int c = 0; c < 8; c++)
                        a3[c] += fmaf(ts, s_w30v[c], s_b3v[c]);
                    bool edge = (wid == 0) | (wid == 3);
                    int px = rg*128 + wid*32 + m32;
                    size_t pb8 = ((size_t)(b << 10) + px) << 3;
                    st8(kout + pb8, a3, edge);
                    if (mode == 1) {
                        float kv1[8], kv3[8], kv4[8], kv5[8], yv[8], r8[8];
                        ld8(ka + pb8, kv1, false);
                        ld8(kb + 2*(size_t)NS + pb8, kv3, false);
                        ld8(kb + 3*(size_t)NS + pb8, kv4, false);
                        ld8(kb + 4*(size_t)NS + pb8, kv5, false);
                        ld8(ya + pb8, yv, false);
                        #pragma unroll
                        for (int c = 0; c < 8; c++)
                            r8[c] = yv[c] + dtc*(B1c*kv1[c] + B3c*kv3[c]
                                    + B4c*kv4[c] + B5c*kv5[c] + B6c*a3[c]);
                        st8(yb + pb8, r8, edge);
                    } else if (mode == 2) {
                        float kv1[8], kv3[8], kv4[8], kv5[8], kv6[8], yv[8], y5v[8];
                        ld8(ka + pb8, kv1, false);
                        ld8(kb + 2*(size_t)NS + pb8, kv3, false);
                        ld8(kb + 3*(size_t)NS + pb8, kv4, false);
                        ld8(kb + 4*(size_t)NS + pb8, kv5, false);
                        ld8(kb + 5*(size_t)NS + pb8, kv6, false);
                        ld8(ya + pb8, yv, false);
                        ld8(yb + pb8, y5v, false);
                        #pragma unroll
                        for (int c = 0; c < 8; c++) {
                            float e = dtc*(E1c*kv1[c] + E3c*kv3[c] + E4c*kv4[c]
                                           + E5c*kv5[c] + E6c*kv6[c] + E7c*a3[c]);
                            float tol = ATOL + RTOL*fmaxf(fabsf(yv[c]), fabsf(y5v[c]));
                            float rr = e / tol;
                            ls += rr*rr;
                        }
                    }
                }
            }
            // per-wave drain then early halo release (no block barrier)
            asm volatile("s_waitcnt vmcnt(0)" ::: "memory");
            if (lane == 0 && wid == 0)
                __hip_atomic_store(&flagT[tile], gev, __ATOMIC_RELAXED,
                                   __HIP_MEMORY_SCOPE_SYSTEM);
            if (lane == 0 && wid == 3)
                __hip_atomic_store(&flagB[tile], gev, __ATOMIC_RELAXED,
                                   __HIP_MEMORY_SCOPE_SYSTEM);
            if (mode == 2) {
                float v = ls;
                #pragma unroll
                for (int off = 1; off < 64; off <<= 1)
                    v += __shfl_xor(v, off, 64);
                if (lane == 0) s_red[wid] = v;
                __syncthreads();
                if (tid == 0) {
                    st_sysf(&partp[tile],
                            s_red[0] + s_red[1] + s_red[2] + s_red[3]);
                    asm volatile("s_waitcnt vmcnt(0)" ::: "memory");
                    __hip_atomic_store(&flags[tile], gev, __ATOMIC_RELAXED,
                                       __HIP_MEMORY_SCOPE_SYSTEM);
                }
            }
        }
    };

    int gev = 1;
    eval(ya, 0, g_cf[5], 0.0f, ka, 0, gev, part);   // k1 = f(t0, y0)
    gev++;

    for (int st = 0; st < 24; st++) {
        if (t >= 1.0f - 1e-7f) break;
        float* partp = part + (size_t)(st & 1)*512;
        for (int e = 0; e < 6; e++) {
            int nc = (e < 5) ? e + 1 : 0;
            const float* src = (e == 5) ? yb : ya;
            float* kout = (e < 5) ? kb + (size_t)(e + 1)*NS : kg;
            int mode = (e == 4) ? 1 : ((e == 5) ? 2 : 0);
            eval(src, nc, g_cf[e], g_ct[e], kout, mode, gev, partp);
            gev++;
        }
        wait_all(gev - 1);   // all tiles finished the err eval (partials at L3)
        float v = ld_sysf(&partp[tid]) + ld_sysf(&partp[tid + 256]);
        #pragma unroll
        for (int off = 1; off < 64; off <<= 1)
            v += __shfl_xor(v, off, 64);
        if (lane == 0) s_red[wid] = v;
        __syncthreads();
        float red0 = s_red[0] + s_red[1] + s_red[2] + s_red[3];
        float err_norm = sqrtf(red0 / (float)NS);
        float dtc = fminf(dt, 1.0f - t);
        bool adv = (err_norm <= 1.0f);
        if (adv) {
            t = t + dtc;
            float* tmp = ya; ya = yb; yb = tmp;   // y <- y5
            tmp = ka; ka = kg; kg = tmp;          // k1 <- k7 (FSAL)
        }
        float safe = fmaxf(err_norm, 1e-10f);
        float factor = fminf(fmaxf(0.9f*powf(safe, -0.2f), 0.2f), 10.0f);
        dt = dtc*factor;
    }

    // flush private interior rows of final y to L3, then publish + wait
    for (int tile = blockIdx.x; tile < 512; tile += nblk) {
        int b = tile >> 3, rg = tile & 7;
        if (tid < 128) {
            int lrow = tid >> 5;
            if (lrow == 1 || lrow == 2) {
                int px = rg*128 + tid;
                float* yp = ya + (((size_t)(b << 10) + px) << 3);
                float4 v0 = *(const float4*)yp;
                float4 v1 = *(const float4*)(yp + 4);
                st_sysf2(yp,     v0.x, v0.y);
                st_sysf2(yp + 2, v0.z, v0.w);
                st_sysf2(yp + 4, v1.x, v1.y);
                st_sysf2(yp + 6, v1.z, v1.w);
            }
        }
    }
    __syncthreads();
    for (int tile = blockIdx.x; tile < 512; tile += nblk)
        if (tid == 0)
            __hip_atomic_store(&flags[tile], gev, __ATOMIC_RELAXED,
                               __HIP_MEMORY_SCOPE_SYSTEM);
    wait_all(gev);

    // final linear head
    for (int bh = blockIdx.x; bh < 64; bh += nblk) {
        float* s_hred = (float*)s_pool;   // 10*256 floats overlay
        float acc[10];
        #pragma unroll
        for (int m = 0; m < 10; m++) acc[m] = 0.0f;
        for (int px = tid; px < 1024; px += 256) {
            const float* yp = ya + (((size_t)(bh << 10) + px) << 3);
            float yv[8];
            #pragma unroll
            for (int h = 0; h < 4; h++) {
                float2 v = ld_sysf2(yp + 2*h);
                yv[2*h] = v.x; yv[2*h+1] = v.y;
            }
            #pragma unroll
            for (int c = 0; c < 8; c++) {
                float v = yv[c];
                #pragma unroll
                for (int m = 0; m < 10; m++)
                    acc[m] = fmaf(v, wl[(size_t)m*8192 + (c << 10) + px], acc[m]);
            }
        }
        #pragma unroll
        for (int m = 0; m < 10; m++) s_hred[m*256 + tid] = acc[m];
        __syncthreads();
        for (int sft = 128; sft > 0; sft >>= 1) {
            if (tid < sft) {
                #pragma unroll
                for (int m = 0; m < 10; m++)
                    s_hred[m*256 + tid] += s_hred[m*256 + tid + sft];
            }
            __syncthreads();
        }
        if (tid < 10) out[bh*10 + tid] = s_hred[tid*256] + bl[tid];
        __syncthreads();
    }
}

// ---------------- host ----------------
extern "C" void kernel_launch(void* const* d_in, const int* in_sizes, int n_in,
                              void* d_out, int out_size, void* d_ws, size_t ws_size,
                              hipStream_t stream)
{
    const float* x  = (const float*)d_in[0];
    const float* w1 = (const float*)d_in[1];
    const float* b1 = (const float*)d_in[2];
    const float* w2 = (const float*)d_in[3];
    const float* b2 = (const float*)d_in[4];
    const float* w3 = (const float*)d_in[5];
    const float* b3 = (const float*)d_in[6];
    const float* wl = (const float*)d_in[7];
    const float* bl = (const float*)d_in[8];
    float* out = (float*)d_out;

    float* F = (float*)d_ws;
    float* part = F + OFF_PART;
    int*   flags = (int*)(F + OFF_FLAG);
    float* tsum = F + OFF_TSUM;
    _Float16* w2p = (_Float16*)(F + OFF_W2P);
    float* y    = F + OFF_Y;
    float* y5   = F + OFF_Y5;
    float* kbp  = F + OFF_K;
    float* wpk  = F + OFF_WPK;
    int*   flagT = (int*)(F + OFF_FT);
    int*   flagB = (int*)(F + OFF_FB);

    k_init<<<NS/256, 256, 0, stream>>>(x, y, flags, flagT, flagB);
    k_prepack<<<144, 256, 0, stream>>>(w1, w2, w3, w2p, tsum, wpk);

    int maxb = 0;
    if (hipOccupancyMaxActiveBlocksPerMultiprocessor(&maxb,
            reinterpret_cast<const void*>(k_ode), 256, 0) != hipSuccess || maxb < 1)
        maxb = 1;
    int cus = 256;
    {
        int dev = 0;
        hipGetDevice(&dev);
        hipDeviceProp_t prop;
        if (hipGetDeviceProperties(&prop, dev) == hipSuccess && prop.multiProcessorCount > 0)
            cus = prop.multiProcessorCount;
    }
    long cap = (long)maxb * (long)cus;
    int gridn = (int)((cap < 512) ? cap : 512);
    if (gridn < 16) gridn = 16;

    k_ode<<<gridn, 256, 0, stream>>>(b1, b2, b3, w2p, tsum, wpk, wl, bl,
                                     y, y5, kbp, part, flags, flagT, flagB, out);
}

// Round 11
// 431.539 us; speedup vs baseline: 1.8131x; 1.8131x over previous
//
#include <hip/hip_runtime.h>
#include <math.h>

namespace {
constexpr int BN = 64;
constexpr int HW = 1024;
constexpr int NS = BN*8*HW;      // 524288

constexpr float C2f = 0.2f, C3f = 0.3f, C4f = 0.8f, C5f = (float)(8.0/9.0);
constexpr float A21 = 0.2f;
constexpr float A31 = (float)(3.0/40.0),  A32 = (float)(9.0/40.0);
constexpr float A41 = (float)(44.0/45.0), A42 = (float)(-56.0/15.0), A43 = (float)(32.0/9.0);
constexpr float A51 = (float)(19372.0/6561.0), A52 = (float)(-25360.0/2187.0),
                A53 = (float)(64448.0/6561.0), A54 = (float)(-212.0/729.0);
constexpr float A61 = (float)(9017.0/3168.0), A62 = (float)(-355.0/33.0),
                A63 = (float)(46732.0/5247.0), A64 = (float)(49.0/176.0),
                A65 = (float)(-5103.0/18656.0);
constexpr float B1c = (float)(35.0/384.0), B3c = (float)(500.0/1113.0),
                B4c = (float)(125.0/192.0), B5c = (float)(-2187.0/6784.0),
                B6c = (float)(11.0/84.0);
constexpr float E1c = (float)(71.0/57600.0), E3c = (float)(-71.0/16695.0),
                E4c = (float)(71.0/1920.0), E5c = (float)(-17253.0/339200.0),
                E6c = (float)(22.0/525.0),  E7c = (float)(-1.0/40.0);
constexpr float RTOL = 1e-3f, ATOL = 1e-3f;

// ws layout (floats / ints)
constexpr size_t OFF_PART = 0;        // 1024 floats (double-buffered by step parity)
constexpr size_t OFF_FLAG = 1024;     // 512 ints (tile fully done; step gate)
constexpr size_t OFF_CNT  = 1536;     // unused, kept
constexpr size_t OFF_TSUM = 1600;     // 576
constexpr size_t OFF_W2P  = 2176;     // 36864 halfs = 18432 floats
constexpr size_t OFF_Y    = 20608;    // y buffers px-major: [b][px][8]
constexpr size_t OFF_Y5   = OFF_Y  + (size_t)NS;
constexpr size_t OFF_K    = OFF_Y5 + (size_t)NS;   // 7*NS (k1..k7, px-major)
constexpr size_t OFF_WPK  = OFF_K + (size_t)7*NS;  // w1t(512) w10(64) w3t(512) w30(8)
constexpr size_t OFF_FT   = OFF_WPK + 1152;        // 512 ints: top-row ready
constexpr size_t OFF_FB   = OFF_FT + 512;          // 512 ints: bottom-row ready

// LDS strides (bytes), both == 4 dwords (mod 32): b128 ops tile banks (R0-style).
constexpr int ACT_STRIDE = 272;   // 192 px rows (6x32), 128B payload
constexpr int H2_STRIDE  = 144;   // 128 px rows, 128B payload
}

__constant__ float g_cf[6][5] = {
    {A21, 0, 0, 0, 0},
    {A31, A32, 0, 0, 0},
    {A41, A42, A43, 0, 0},
    {A51, A52, A53, A54, 0},
    {A61, A62, A63, A64, A65},
    {0, 0, 0, 0, 0}};
__constant__ float g_ct[6] = {C2f, C3f, C4f, C5f, 1.0f, 1.0f};

typedef _Float16 hfrag8 __attribute__((ext_vector_type(8)));
typedef float f32x16 __attribute__((ext_vector_type(16)));

union HU { hfrag8 h; unsigned u[4]; uint4 v; };

// ---- system-scope (L3-coherent) accessors ----
__device__ __forceinline__ float ld_sysf(const float* p) {
    return __hip_atomic_load(p, __ATOMIC_RELAXED, __HIP_MEMORY_SCOPE_SYSTEM);
}
__device__ __forceinline__ float2 ld_sysf2(const float* p) {
    union { unsigned long long u; float2 f; } c;
    c.u = __hip_atomic_load((const unsigned long long*)p, __ATOMIC_RELAXED,
                            __HIP_MEMORY_SCOPE_SYSTEM);
    return c.f;
}
__device__ __forceinline__ void st_sysf(float* p, float v) {
    __hip_atomic_store(p, v, __ATOMIC_RELAXED, __HIP_MEMORY_SCOPE_SYSTEM);
}
__device__ __forceinline__ void st_sysf2(float* p, float a, float b) {
    union { unsigned long long u; float2 f; } c;
    c.f = make_float2(a, b);
    __hip_atomic_store((unsigned long long*)p, c.u, __ATOMIC_RELAXED,
                       __HIP_MEMORY_SCOPE_SYSTEM);
}

// 8-float load/store; sys = NEIGHBOR-written (L3) vs self-written (L2 plain)
__device__ __forceinline__ void ld8(const float* p, float* v, bool sys) {
    if (sys) {
        #pragma unroll
        for (int h = 0; h < 4; h++) {
            float2 t = ld_sysf2(p + 2*h);
            v[2*h] = t.x; v[2*h+1] = t.y;
        }
    } else {
        float4 a = *(const float4*)p;
        float4 b = *(const float4*)(p + 4);
        v[0]=a.x; v[1]=a.y; v[2]=a.z; v[3]=a.w;
        v[4]=b.x; v[5]=b.y; v[6]=b.z; v[7]=b.w;
    }
}
__device__ __forceinline__ void st8(float* p, const float* v, bool sys) {
    if (sys) {
        st_sysf2(p,     v[0], v[1]);
        st_sysf2(p + 2, v[2], v[3]);
        st_sysf2(p + 4, v[4], v[5]);
        st_sysf2(p + 6, v[6], v[7]);
    } else {
        *(float4*)p       = make_float4(v[0], v[1], v[2], v[3]);
        *(float4*)(p + 4) = make_float4(v[4], v[5], v[6], v[7]);
    }
}

// ---------------- init ----------------
__global__ __launch_bounds__(256)
void k_init(const float* __restrict__ x, float* __restrict__ y,
            int* __restrict__ flags, int* __restrict__ flagT,
            int* __restrict__ flagB)
{
    int idx = blockIdx.x*256 + threadIdx.x;           // < NS
    int b = idx >> 13, px = (idx >> 3) & 1023, c = idx & 7;
    y[idx] = (c < 3) ? x[(size_t)(b*3 + c)*1024 + px] : 0.0f;
    if (idx < 512) { flags[idx] = 0; flagT[idx] = 0; flagB[idx] = 0; }
}

// ---------------- prepack ----------------
__global__ __launch_bounds__(256)
void k_prepack(const float* __restrict__ w1, const float* __restrict__ w2,
               const float* __restrict__ w3, _Float16* __restrict__ w2p,
               float* __restrict__ tsum, float* __restrict__ wpk)
{
    int gid = blockIdx.x*256 + threadIdx.x;
    if (gid < 36864) {
        int j    = gid & 7;
        int lane = (gid >> 3) & 63;
        int nt   = (gid >> 9) & 1;
        int ks   = (gid >> 10) & 3;
        int tap  = gid >> 12;            // 0..8
        int oc = nt*32 + (lane & 31);
        int kpos = ks*16 + (lane >> 5)*8 + j;
        int oct = kpos >> 5, q2b = (kpos >> 4) & 1, rr = kpos & 15;
        int ic = oct*32 + (rr & 3) + (q2b << 2) + ((rr >> 2) << 3);  // inv-pi
        w2p[gid] = (_Float16)w2[oc*585 + (1 + ic)*9 + tap];
    }
    if (gid < 576) {
        int oc = gid & 63, combo = gid >> 6;       // 0..8
        int rcase = combo / 3, ccase = combo % 3;
        float s = 0.0f;
        for (int kh = 0; kh < 3; kh++) {
            if ((rcase == 1 && kh == 0) || (rcase == 2 && kh == 2)) continue;
            for (int kw = 0; kw < 3; kw++) {
                if ((ccase == 1 && kw == 0) || (ccase == 2 && kw == 2)) continue;
                s += w2[oc*585 + kh*3 + kw];
            }
        }
        tsum[gid] = s;
    }
    if (gid < 512) wpk[gid] = w1[(gid & 63)*9 + 1 + (gid >> 6)];
    if (gid < 64)  wpk[512 + gid] = w1[gid*9];
    if (gid < 512) wpk[576 + gid] = w3[(gid & 7)*65 + 1 + (gid >> 3)];
    if (gid < 8)   wpk[1088 + gid] = w3[gid*65];
}

// ---------------- the whole ODE solve ----------------
// R11 = R6 base + conv2 K-half chain split with STATIC indexing (R10's
// acc2[ri][ks>>1] was runtime-indexed -> scratch -> 1.5GB spill traffic).
// Two #pragma unroll 1 loops (ks 0-1, ks 2-3), named accumulators accA/accB,
// all indices compile-time. 4 independent MFMA chains of 18.
__global__ void __launch_bounds__(256, 2)
k_ode(const float* __restrict__ b1, const float* __restrict__ b2,
      const float* __restrict__ b3, const _Float16* __restrict__ w2p,
      const float* __restrict__ tsumg, const float* __restrict__ wpk,
      const float* __restrict__ wl, const float* __restrict__ bl,
      float* __restrict__ ybuf, float* __restrict__ y5buf,
      float* __restrict__ kb, float* __restrict__ part,
      int* __restrict__ flags, int* __restrict__ flagT,
      int* __restrict__ flagB, float* __restrict__ out)
{
    __shared__ __align__(16) unsigned char s_pool[192*ACT_STRIDE]; // 52224
    __shared__ __align__(16) unsigned char s_h2[128*H2_STRIDE];    // 18432
    __shared__ float s_tsum[576];
    __shared__ float s_b2v[64], s_b1v[64], s_w10v[64];
    __shared__ float s_w30v[8], s_b3v[8];
    __shared__ float s_red[8];

    const int tid = threadIdx.x;
    const int nblk = gridDim.x;
    const int lane = tid & 63;
    const int m32 = lane & 31, q2 = lane >> 5;
    const int rp = tid >> 7;          // row-pair for conv2
    const int np = (tid >> 6) & 1;    // oc-half for conv2
    const int wid = tid >> 6;         // wave id
    const bool lz32 = (lane == 32);
    const bool lz31 = (lane == 31);

    if (tid < 64) {
        s_b2v[tid] = b2[tid];
        s_b1v[tid] = b1[tid];
        s_w10v[tid] = wpk[512 + tid];
    }
    if (tid < 8) { s_w30v[tid] = wpk[1088 + tid]; s_b3v[tid] = b3[tid]; }
    for (int i = tid; i < 576; i += 256) s_tsum[i] = tsumg[i];
    __syncthreads();

    // resident conv1 A-frags: lo (k=0..7 live) and hi (k=8..15 live)
    hfrag8 w1lo[2], w1hi[2];
    #pragma unroll
    for (int oct = 0; oct < 2; oct++)
        #pragma unroll
        for (int j = 0; j < 8; j++) {
            _Float16 wv = (_Float16)wpk[j*64 + oct*32 + m32];
            w1lo[oct][j] = q2 ? (_Float16)0.0f : wv;
            w1hi[oct][j] = q2 ? wv : (_Float16)0.0f;
        }
    // resident conv3 A-frags (channel positions permuted by inv-pi)
    hfrag8 w3f[4];
    #pragma unroll
    for (int kst = 0; kst < 4; kst++)
        #pragma unroll
        for (int j = 0; j < 8; j++) {
            int kpos = kst*16 + q2*8 + j;
            int oct = kpos >> 5, q2b = (kpos >> 4) & 1, rr = kpos & 15;
            int ch = oct*32 + (rr & 3) + (q2b << 2) + ((rr >> 2) << 3);
            w3f[kst][j] = (m32 < 8) ? (_Float16)wpk[576 + ch*8 + m32]
                                    : (_Float16)0.0f;
        }

    float t = 0.0f, dt = 0.1f;
    float* ya = ybuf; float* yb = y5buf;
    float* ka = kb;  float* kg = kb + 6*(size_t)NS;

    auto wait_all = [&](int target) {
        for (;;) {
            bool ok = (__hip_atomic_load(&flags[tid], __ATOMIC_RELAXED,
                           __HIP_MEMORY_SCOPE_SYSTEM) >= target)
                   && (__hip_atomic_load(&flags[tid + 256], __ATOMIC_RELAXED,
                           __HIP_MEMORY_SCOPE_SYSTEM) >= target);
            if (__syncthreads_and((int)ok)) break;
            __builtin_amdgcn_s_sleep(2);
        }
    };

    auto eval = [&](const float* src, int nc, const float* cf, float ctv,
                    float* kout, int mode, int gev, float* partp) {
        float dtc = fminf(dt, 1.0f - t);
        float ts  = t + ctv*dtc;

        for (int tile = blockIdx.x; tile < 512; tile += nblk) {
            int b = tile >> 3, rg = tile & 7;

            // ---- z-combine (memory path) ----
            auto zload = [&](int lr) {
                HU pz; pz.v = make_uint4(0u,0u,0u,0u);
                int r = rg*4 - 1 + lr;
                if ((unsigned)lr < 6u && (unsigned)r < 32u) {
                    bool nbr = (lr == 0) | (lr == 5);   // neighbor-written only
                    int px = (r << 5) + m32;
                    size_t pb8 = ((size_t)(b << 10) + px) << 3;
                    float kv[5][8], sv[8];
                    if (nbr) {
                        #pragma unroll
                        for (int j = 0; j < 5; j++) if (j < nc) {
                            const float* kp = (j == 0 ? ka : kb + (size_t)j*NS) + pb8;
                            #pragma unroll
                            for (int h = 0; h < 4; h++) {
                                float2 t2 = ld_sysf2(kp + 2*h);
                                kv[j][2*h] = t2.x; kv[j][2*h+1] = t2.y;
                            }
                        }
                        #pragma unroll
                        for (int h = 0; h < 4; h++) {
                            float2 t2 = ld_sysf2(src + pb8 + 2*h);
                            sv[2*h] = t2.x; sv[2*h+1] = t2.y;
                        }
                    } else {
                        #pragma unroll
                        for (int j = 0; j < 5; j++) if (j < nc) {
                            const float* kp = (j == 0 ? ka : kb + (size_t)j*NS) + pb8;
                            float4 a4 = *(const float4*)kp;
                            float4 b4 = *(const float4*)(kp + 4);
                            kv[j][0]=a4.x; kv[j][1]=a4.y; kv[j][2]=a4.z; kv[j][3]=a4.w;
                            kv[j][4]=b4.x; kv[j][5]=b4.y; kv[j][6]=b4.z; kv[j][7]=b4.w;
                        }
                        float4 a4 = *(const float4*)(src + pb8);
                        float4 b4 = *(const float4*)(src + pb8 + 4);
                        sv[0]=a4.x; sv[1]=a4.y; sv[2]=a4.z; sv[3]=a4.w;
                        sv[4]=b4.x; sv[5]=b4.y; sv[6]=b4.z; sv[7]=b4.w;
                    }
                    float s_[8] = {0,0,0,0,0,0,0,0};
                    #pragma unroll
                    for (int j = 0; j < 5; j++) if (j < nc) {
                        float a = cf[j];
                        #pragma unroll
                        for (int c = 0; c < 8; c++) s_[c] = fmaf(a, kv[j][c], s_[c]);
                    }
                    #pragma unroll
                    for (int c = 0; c < 8; c++)
                        pz.h[c] = (_Float16)(sv[c] + dtc*s_[c]);
                }
                return pz;
            };

            HU pz;
            if (q2 == 0) pz = zload(wid + 1);      // own rows 1..4 (issued pre-spin)
            if (gev > 1 && q2 == 1 && (wid == 0 || wid == 3)) {
                bool need = (wid == 0) ? (rg > 0) : (rg < 7);
                if (need) {
                    const int* fp = (wid == 0) ? &flagB[tile-1] : &flagT[tile+1];
                    while (__hip_atomic_load(fp, __ATOMIC_RELAXED,
                                             __HIP_MEMORY_SCOPE_SYSTEM) < gev-1)
                        __builtin_amdgcn_s_sleep(1);
                }
            }
            if (q2 == 1) pz = zload((wid == 0) ? 0 : ((wid == 3) ? 5 : -1));

            // ---- conv1 via MFMA from registers; act write (pi-permuted) ----
            auto wr_act = [&](int lr, const f32x16& a1, int oct, bool valid) {
                unsigned words[8];
                #pragma unroll
                for (int pr = 0; pr < 8; pr++) {
                    int r0 = 2*pr;
                    int oc0 = oct*32 + (r0 & 3) + 8*(r0 >> 2) + 4*q2;
                    float v0 = valid ? fmaxf(a1[r0]   + ts*s_w10v[oc0]
                                             + s_b1v[oc0],   0.0f) : 0.0f;
                    float v1 = valid ? fmaxf(a1[r0+1] + ts*s_w10v[oc0+1]
                                             + s_b1v[oc0+1], 0.0f) : 0.0f;
                    union { _Float16 h[2]; unsigned u; } pk;
                    pk.h[0] = (_Float16)v0; pk.h[1] = (_Float16)v1;
                    words[pr] = pk.u;
                }
                unsigned char* basep = s_pool + (size_t)(lr*32 + m32)*ACT_STRIDE
                                       + oct*64 + q2*32;
                *(uint4*)basep        = make_uint4(words[0],words[1],words[2],words[3]);
                *(uint4*)(basep + 16) = make_uint4(words[4],words[5],words[6],words[7]);
            };
            {
                f32x16 zz = (f32x16)(0.0f);
                f32x16 c0 = __builtin_amdgcn_mfma_f32_32x32x16_f16(w1lo[0], pz.h, zz, 0,0,0);
                f32x16 c1 = __builtin_amdgcn_mfma_f32_32x32x16_f16(w1lo[1], pz.h, zz, 0,0,0);
                wr_act(wid + 1, c0, 0, true);
                wr_act(wid + 1, c1, 1, true);
                if (wid == 0 || wid == 3) {
                    int lrh = (wid == 0) ? 0 : 5;
                    bool vh = (unsigned)(rg*4 - 1 + lrh) < 32u;
                    f32x16 d0 = __builtin_amdgcn_mfma_f32_32x32x16_f16(w1hi[0], pz.h, zz, 0,0,0);
                    f32x16 d1 = __builtin_amdgcn_mfma_f32_32x32x16_f16(w1hi[1], pz.h, zz, 0,0,0);
                    wr_act(lrh, d0, 0, vh);
                    wr_act(lrh, d1, 1, vh);
                }
            }
            __syncthreads();   // BARRIER-A: act complete

            // ---- conv2: two half-K loops, named accumulators (static idx) ----
            f32x16 accA0 = (f32x16)(0.0f), accA1 = (f32x16)(0.0f);
            f32x16 accB0 = (f32x16)(0.0f), accB1 = (f32x16)(0.0f);
            {
                const unsigned char* actb = (const unsigned char*)s_pool;
                #pragma unroll 1
                for (int ks = 0; ks < 2; ks++) {
                    HU fc[4], d0[4], d2[4];
                    #pragma unroll
                    for (int l = 0; l < 4; l++) {
                        const unsigned char* p = actb
                            + (size_t)((rp*2 + l)*32 + m32)*ACT_STRIDE
                            + ks*32 + q2*16;
                        fc[l].v = *(const uint4*)p;
                    }
                    #pragma unroll
                    for (int l = 0; l < 4; l++) {
                        #pragma unroll
                        for (int i = 0; i < 4; i++) {
                            unsigned s0 = (unsigned)__builtin_amdgcn_update_dpp(
                                0, (int)fc[l].u[i], 0x138, 0xF, 0xF, true); // wave_shr:1
                            d0[l].u[i] = lz32 ? 0u : s0;
                            unsigned s2 = (unsigned)__builtin_amdgcn_update_dpp(
                                0, (int)fc[l].u[i], 0x130, 0xF, 0xF, true); // wave_shl:1
                            d2[l].u[i] = lz31 ? 0u : s2;
                        }
                    }
                    #pragma unroll
                    for (int kh = 0; kh < 3; kh++) {
                        #pragma unroll
                        for (int kw = 0; kw < 3; kw++) {
                            int tap = kh*3 + kw;
                            hfrag8 aw = *(const hfrag8*)
                                (w2p + (size_t)((tap*4 + ks)*2 + np)*512 + lane*8);
                            {
                                hfrag8 bf = (kw == 0) ? d0[kh].h
                                          : ((kw == 1) ? fc[kh].h : d2[kh].h);
                                accA0 = __builtin_amdgcn_mfma_f32_32x32x16_f16(
                                    aw, bf, accA0, 0, 0, 0);
                            }
                            {
                                hfrag8 bf = (kw == 0) ? d0[kh+1].h
                                          : ((kw == 1) ? fc[kh+1].h : d2[kh+1].h);
                                accA1 = __builtin_amdgcn_mfma_f32_32x32x16_f16(
                                    aw, bf, accA1, 0, 0, 0);
                            }
                        }
                    }
                }
                #pragma unroll 1
                for (int ks = 2; ks < 4; ks++) {
                    HU fc[4], d0[4], d2[4];
                    #pragma unroll
                    for (int l = 0; l < 4; l++) {
                        const unsigned char* p = actb
                            + (size_t)((rp*2 + l)*32 + m32)*ACT_STRIDE
                            + ks*32 + q2*16;
                        fc[l].v = *(const uint4*)p;
                    }
                    #pragma unroll
                    for (int l = 0; l < 4; l++) {
                        #pragma unroll
                        for (int i = 0; i < 4; i++) {
                            unsigned s0 = (unsigned)__builtin_amdgcn_update_dpp(
                                0, (int)fc[l].u[i], 0x138, 0xF, 0xF, true); // wave_shr:1
                            d0[l].u[i] = lz32 ? 0u : s0;
                            unsigned s2 = (unsigned)__builtin_amdgcn_update_dpp(
                                0, (int)fc[l].u[i], 0x130, 0xF, 0xF, true); // wave_shl:1
                            d2[l].u[i] = lz31 ? 0u : s2;
                        }
                    }
                    #pragma unroll
                    for (int kh = 0; kh < 3; kh++) {
                        #pragma unroll
                        for (int kw = 0; kw < 3; kw++) {
                            int tap = kh*3 + kw;
                            hfrag8 aw = *(const hfrag8*)
                                (w2p + (size_t)((tap*4 + ks)*2 + np)*512 + lane*8);
                            {
                                hfrag8 bf = (kw == 0) ? d0[kh].h
                                          : ((kw == 1) ? fc[kh].h : d2[kh].h);
                                accB0 = __builtin_amdgcn_mfma_f32_32x32x16_f16(
                                    aw, bf, accB0, 0, 0, 0);
                            }
                            {
                                hfrag8 bf = (kw == 0) ? d0[kh+1].h
                                          : ((kw == 1) ? fc[kh+1].h : d2[kh+1].h);
                                accB1 = __builtin_amdgcn_mfma_f32_32x32x16_f16(
                                    aw, bf, accB1, 0, 0, 0);
                            }
                        }
                    }
                }
            }

            // ---- conv2 epilogue -> h2 (pi-permuted px-major fp16) ----
            {
                int ccase = (m32 == 0) ? 1 : ((m32 == 31) ? 2 : 0);
                #pragma unroll
                for (int ri = 0; ri < 2; ri++) {
                    int pg = rp*2 + ri;
                    int r_out = rg*4 + pg;
                    int rcase = (r_out == 0) ? 1 : ((r_out == 31) ? 2 : 0);
                    const float* tsb = &s_tsum[(rcase*3 + ccase)*64];
                    int px = pg*32 + m32;
                    unsigned words[8];
                    #pragma unroll
                    for (int pr = 0; pr < 8; pr++) {
                        int r0 = 2*pr;
                        int oc0 = np*32 + (r0 & 3) + 8*(r0 >> 2) + 4*q2;
                        float a0 = (ri == 0) ? (accA0[r0]   + accB0[r0])
                                             : (accA1[r0]   + accB1[r0]);
                        float a1 = (ri == 0) ? (accA0[r0+1] + accB0[r0+1])
                                             : (accA1[r0+1] + accB1[r0+1]);
                        float v0 = fmaxf(a0 + ts*tsb[oc0]   + s_b2v[oc0],   0.0f);
                        float v1 = fmaxf(a1 + ts*tsb[oc0+1] + s_b2v[oc0+1], 0.0f);
                        union { _Float16 h[2]; unsigned u; } pk;
                        pk.h[0] = (_Float16)v0; pk.h[1] = (_Float16)v1;
                        words[pr] = pk.u;
                    }
                    unsigned char* basep = s_h2 + (size_t)px*H2_STRIDE
                                           + np*64 + q2*32;
                    *(uint4*)basep        = make_uint4(words[0],words[1],words[2],words[3]);
                    *(uint4*)(basep + 16) = make_uint4(words[4],words[5],words[6],words[7]);
                }
            }
            __syncthreads();   // BARRIER-B: h2 complete

            // ---- conv3 via MFMA + mode epilogues ----
            float ls = 0.0f;
            {
                f32x16 a3a = (f32x16)(0.0f);
                #pragma unroll
                for (int kst = 0; kst < 4; kst++) {
                    HU f;
                    const unsigned char* p = s_h2
                        + (size_t)(wid*32 + m32)*H2_STRIDE + kst*32 + q2*16;
                    f.v = *(const uint4*)p;
                    a3a = __builtin_amdgcn_mfma_f32_32x32x16_f16(
                        w3f[kst], f.h, a3a, 0, 0, 0);
                }
                float a3[8];
                #pragma unroll
                for (int r = 0; r < 4; r++) {
                    float own = a3a[r];
                    float oth = __shfl(own, lane ^ 32, 64);
                    a3[r]     = q2 ? oth : own;
                    a3[4 + r] = q2 ? own : oth;
                }
                if (q2 == 0) {
                    #pragma unroll
                    for (int c = 0; c < 8; c++)
                        a3[c] += fmaf(ts, s_w30v[c], s_b3v[c]);
                    bool edge = (wid == 0) | (wid == 3);
                    int px = rg*128 + wid*32 + m32;
                    size_t pb8 = ((size_t)(b << 10) + px) << 3;
                    st8(kout + pb8, a3, edge);
                    if (mode == 1) {
                        float kv1[8], kv3[8], kv4[8], kv5[8], yv[8], r8[8];
                        ld8(ka + pb8, kv1, false);
                        ld8(kb + 2*(size_t)NS + pb8, kv3, false);
                        ld8(kb + 3*(size_t)NS + pb8, kv4, false);
                        ld8(kb + 4*(size_t)NS + pb8, kv5, false);
                        ld8(ya + pb8, yv, false);
                        #pragma unroll
                        for (int c = 0; c < 8; c++)
                            r8[c] = yv[c] + dtc*(B1c*kv1[c] + B3c*kv3[c]
                                    + B4c*kv4[c] + B5c*kv5[c] + B6c*a3[c]);
                        st8(yb + pb8, r8, edge);
                    } else if (mode == 2) {
                        float kv1[8], kv3[8], kv4[8], kv5[8], kv6[8], yv[8], y5v[8];
                        ld8(ka + pb8, kv1, false);
                        ld8(kb + 2*(size_t)NS + pb8, kv3, false);
                        ld8(kb + 3*(size_t)NS + pb8, kv4, false);
                        ld8(kb + 4*(size_t)NS + pb8, kv5, false);
                        ld8(kb + 5*(size_t)NS + pb8, kv6, false);
                        ld8(ya + pb8, yv, false);
                        ld8(yb + pb8, y5v, false);
                        #pragma unroll
                        for (int c = 0; c < 8; c++) {
                            float e = dtc*(E1c*kv1[c] + E3c*kv3[c] + E4c*kv4[c]
                                           + E5c*kv5[c] + E6c*kv6[c] + E7c*a3[c]);
                            float tol = ATOL + RTOL*fmaxf(fabsf(yv[c]), fabsf(y5v[c]));
                            float rr = e / tol;
                            ls += rr*rr;
                        }
                    }
                }
            }
            // per-wave drain then early halo release (no block barrier)
            asm volatile("s_waitcnt vmcnt(0)" ::: "memory");
            if (lane == 0 && wid == 0)
                __hip_atomic_store(&flagT[tile], gev, __ATOMIC_RELAXED,
                                   __HIP_MEMORY_SCOPE_SYSTEM);
            if (lane == 0 && wid == 3)
                __hip_atomic_store(&flagB[tile], gev, __ATOMIC_RELAXED,
                                   __HIP_MEMORY_SCOPE_SYSTEM);
            if (mode == 2) {
                float v = ls;
                #pragma unroll
                for (int off = 1; off < 64; off <<= 1)
                    v += __shfl_xor(v, off, 64);
                if (lane == 0) s_red[wid] = v;
                __syncthreads();
                if (tid == 0) {
                    st_sysf(&partp[tile],
                            s_red[0] + s_red[1] + s_red[2] + s_red[3]);
                    asm volatile("s_waitcnt vmcnt(0)" ::: "memory");
                    __hip_atomic_store(&flags[tile], gev, __ATOMIC_RELAXED,
                                       __HIP_MEMORY_SCOPE_SYSTEM);
                }
            }
        }
    };

    int gev = 1;
    eval(ya, 0, g_cf[5], 0.0f, ka, 0, gev, part);   // k1 = f(t0, y0)
    gev++;

    for (int st = 0; st < 24; st++) {
        if (t >= 1.0f - 1e-7f) break;
        float* partp = part + (size_t)(st & 1)*512;
        for (int e = 0; e < 6; e++) {
            int nc = (e < 5) ? e + 1 : 0;
            const float* src = (e == 5) ? yb : ya;
            float* kout = (e < 5) ? kb + (size_t)(e + 1)*NS : kg;
            int mode = (e == 4) ? 1 : ((e == 5) ? 2 : 0);
            eval(src, nc, g_cf[e], g_ct[e], kout, mode, gev, partp);
            gev++;
        }
        wait_all(gev - 1);   // all tiles finished the err eval (partials at L3)
        float v = ld_sysf(&partp[tid]) + ld_sysf(&partp[tid + 256]);
        #pragma unroll
        for (int off = 1; off < 64; off <<= 1)
            v += __shfl_xor(v, off, 64);
        if (lane == 0) s_red[wid] = v;
        __syncthreads();
        float red0 = s_red[0] + s_red[1] + s_red[2] + s_red[3];
        float err_norm = sqrtf(red0 / (float)NS);
        float dtc = fminf(dt, 1.0f - t);
        bool adv = (err_norm <= 1.0f);
        if (adv) {
            t = t + dtc;
            float* tmp = ya; ya = yb; yb = tmp;   // y <- y5
            tmp = ka; ka = kg; kg = tmp;          // k1 <- k7 (FSAL)
        }
        float safe = fmaxf(err_norm, 1e-10f);
        float factor = fminf(fmaxf(0.9f*powf(safe, -0.2f), 0.2f), 10.0f);
        dt = dtc*factor;
    }

    // flush private interior rows of final y to L3, then publish + wait
    for (int tile = blockIdx.x; tile < 512; tile += nblk) {
        int b = tile >> 3, rg = tile & 7;
        if (tid < 128) {
            int lrow = tid >> 5;
            if (lrow == 1 || lrow == 2) {
                int px = rg*128 + tid;
                float* yp = ya + (((size_t)(b << 10) + px) << 3);
                float4 v0 = *(const float4*)yp;
                float4 v1 = *(const float4*)(yp + 4);
                st_sysf2(yp,     v0.x, v0.y);
                st_sysf2(yp + 2, v0.z, v0.w);
                st_sysf2(yp + 4, v1.x, v1.y);
                st_sysf2(yp + 6, v1.z, v1.w);
            }
        }
    }
    __syncthreads();
    for (int tile = blockIdx.x; tile < 512; tile += nblk)
        if (tid == 0)
            __hip_atomic_store(&flags[tile], gev, __ATOMIC_RELAXED,
                               __HIP_MEMORY_SCOPE_SYSTEM);
    wait_all(gev);

    // final linear head
    for (int bh = blockIdx.x; bh < 64; bh += nblk) {
        float* s_hred = (float*)s_pool;   // 10*256 floats overlay
        float acc[10];
        #pragma unroll
        for (int m = 0; m < 10; m++) acc[m] = 0.0f;
        for (int px = tid; px < 1024; px += 256) {
            const float* yp = ya + (((size_t)(bh << 10) + px) << 3);
            float yv[8];
            #pragma unroll
            for (int h = 0; h < 4; h++) {
                float2 v = ld_sysf2(yp + 2*h);
                yv[2*h] = v.x; yv[2*h+1] = v.y;
            }
            #pragma unroll
            for (int c = 0; c < 8; c++) {
                float v = yv[c];
                #pragma unroll
                for (int m = 0; m < 10; m++)
                    acc[m] = fmaf(v, wl[(size_t)m*8192 + (c << 10) + px], acc[m]);
            }
        }
        #pragma unroll
        for (int m = 0; m < 10; m++) s_hred[m*256 + tid] = acc[m];
        __syncthreads();
        for (int sft = 128; sft > 0; sft >>= 1) {
            if (tid < sft) {
                #pragma unroll
                for (int m = 0; m < 10; m++)
                    s_hred[m*256 + tid] += s_hred[m*256 + tid + sft];
            }
            __syncthreads();
        }
        if (tid < 10) out[bh*10 + tid] = s_hred[tid*256] + bl[tid];
        __syncthreads();
    }
}

// ---------------- host ----------------
extern "C" void kernel_launch(void* const* d_in, const int* in_sizes, int n_in,
                              void* d_out, int out_size, void* d_ws, size_t ws_size,
                              hipStream_t stream)
{
    const float* x  = (const float*)d_in[0];
    const float* w1 = (const float*)d_in[1];
    const float* b1 = (const float*)d_in[2];
    const float* w2 = (const float*)d_in[3];
    const float* b2 = (const float*)d_in[4];
    const float* w3 = (const float*)d_in[5];
    const float* b3 = (const float*)d_in[6];
    const float* wl = (const float*)d_in[7];
    const float* bl = (const float*)d_in[8];
    float* out = (float*)d_out;

    float* F = (float*)d_ws;
    float* part = F + OFF_PART;
    int*   flags = (int*)(F + OFF_FLAG);
    float* tsum = F + OFF_TSUM;
    _Float16* w2p = (_Float16*)(F + OFF_W2P);
    float* y    = F + OFF_Y;
    float* y5   = F + OFF_Y5;
    float* kbp  = F + OFF_K;
    float* wpk  = F + OFF_WPK;
    int*   flagT = (int*)(F + OFF_FT);
    int*   flagB = (int*)(F + OFF_FB);

    k_init<<<NS/256, 256, 0, stream>>>(x, y, flags, flagT, flagB);
    k_prepack<<<144, 256, 0, stream>>>(w1, w2, w3, w2p, tsum, wpk);

    int maxb = 0;
    if (hipOccupancyMaxActiveBlocksPerMultiprocessor(&maxb,
            reinterpret_cast<const void*>(k_ode), 256, 0) != hipSuccess || maxb < 1)
        maxb = 1;
    int cus = 256;
    {
        int dev = 0;
        hipGetDevice(&dev);
        hipDeviceProp_t prop;
        if (hipGetDeviceProperties(&prop, dev) == hipSuccess && prop.multiProcessorCount > 0)
            cus = prop.multiProcessorCount;
    }
    long cap = (long)maxb * (long)cus;
    int gridn = (int)((cap < 512) ? cap : 512);
    if (gridn < 16) gridn = 16;

    k_ode<<<gridn, 256, 0, stream>>>(b1, b2, b3, w2p, tsum, wpk, wl, bl,
                                     y, y5, kbp, part, flags, flagT, flagB, out);
}

// Round 12
// 390.629 us; speedup vs baseline: 2.0030x; 1.1047x over previous
//
#include <hip/hip_runtime.h>
#include <math.h>

namespace {
constexpr int BN = 64;
constexpr int HW = 1024;
constexpr int NS = BN*8*HW;      // 524288

constexpr float C2f = 0.2f, C3f = 0.3f, C4f = 0.8f, C5f = (float)(8.0/9.0);
constexpr float A21 = 0.2f;
constexpr float A31 = (float)(3.0/40.0),  A32 = (float)(9.0/40.0);
constexpr float A41 = (float)(44.0/45.0), A42 = (float)(-56.0/15.0), A43 = (float)(32.0/9.0);
constexpr float A51 = (float)(19372.0/6561.0), A52 = (float)(-25360.0/2187.0),
                A53 = (float)(64448.0/6561.0), A54 = (float)(-212.0/729.0);
constexpr float A61 = (float)(9017.0/3168.0), A62 = (float)(-355.0/33.0),
                A63 = (float)(46732.0/5247.0), A64 = (float)(49.0/176.0),
                A65 = (float)(-5103.0/18656.0);
constexpr float B1c = (float)(35.0/384.0), B3c = (float)(500.0/1113.0),
                B4c = (float)(125.0/192.0), B5c = (float)(-2187.0/6784.0),
                B6c = (float)(11.0/84.0);
constexpr float E1c = (float)(71.0/57600.0), E3c = (float)(-71.0/16695.0),
                E4c = (float)(71.0/1920.0), E5c = (float)(-17253.0/339200.0),
                E6c = (float)(22.0/525.0),  E7c = (float)(-1.0/40.0);
constexpr float RTOL = 1e-3f, ATOL = 1e-3f;

// ws layout (floats / ints)
constexpr size_t OFF_PART = 0;        // 1024 floats (double-buffered by step parity)
constexpr size_t OFF_FLAG = 1024;     // 512 ints (tile fully done; step gate)
constexpr size_t OFF_CNT  = 1536;     // unused, kept
constexpr size_t OFF_TSUM = 1600;     // 576
constexpr size_t OFF_W2P  = 2176;     // 36864 halfs = 18432 floats
constexpr size_t OFF_Y    = 20608;    // y buffers px-major: [b][px][8]
constexpr size_t OFF_Y5   = OFF_Y  + (size_t)NS;
constexpr size_t OFF_K    = OFF_Y5 + (size_t)NS;   // 7*NS (k1..k7, px-major)
constexpr size_t OFF_WPK  = OFF_K + (size_t)7*NS;  // w1t(512) w10(64) w3t(512) w30(8)
constexpr size_t OFF_FT   = OFF_WPK + 1152;        // 512 ints: top-row ready
constexpr size_t OFF_FB   = OFF_FT + 512;          // 512 ints: bottom-row ready

// LDS strides (bytes), both == 4 dwords (mod 32): b128 ops tile banks (R0-style).
constexpr int ACT_STRIDE = 272;   // 192 px rows (6x32), 128B payload
constexpr int H2_STRIDE  = 144;   // 128 px rows, 128B payload
}

__constant__ float g_cf[6][5] = {
    {A21, 0, 0, 0, 0},
    {A31, A32, 0, 0, 0},
    {A41, A42, A43, 0, 0},
    {A51, A52, A53, A54, 0},
    {A61, A62, A63, A64, A65},
    {0, 0, 0, 0, 0}};
__constant__ float g_ct[6] = {C2f, C3f, C4f, C5f, 1.0f, 1.0f};

typedef _Float16 hfrag8 __attribute__((ext_vector_type(8)));
typedef float f32x16 __attribute__((ext_vector_type(16)));

union HU { hfrag8 h; unsigned u[4]; uint4 v; };

// ---- system-scope (L3-coherent) accessors ----
__device__ __forceinline__ float ld_sysf(const float* p) {
    return __hip_atomic_load(p, __ATOMIC_RELAXED, __HIP_MEMORY_SCOPE_SYSTEM);
}
__device__ __forceinline__ float2 ld_sysf2(const float* p) {
    union { unsigned long long u; float2 f; } c;
    c.u = __hip_atomic_load((const unsigned long long*)p, __ATOMIC_RELAXED,
                            __HIP_MEMORY_SCOPE_SYSTEM);
    return c.f;
}
__device__ __forceinline__ void st_sysf(float* p, float v) {
    __hip_atomic_store(p, v, __ATOMIC_RELAXED, __HIP_MEMORY_SCOPE_SYSTEM);
}
__device__ __forceinline__ void st_sysf2(float* p, float a, float b) {
    union { unsigned long long u; float2 f; } c;
    c.f = make_float2(a, b);
    __hip_atomic_store((unsigned long long*)p, c.u, __ATOMIC_RELAXED,
                       __HIP_MEMORY_SCOPE_SYSTEM);
}

// 8-float load/store; sys = NEIGHBOR-written (L3) vs self-written (L2 plain)
__device__ __forceinline__ void ld8(const float* p, float* v, bool sys) {
    if (sys) {
        #pragma unroll
        for (int h = 0; h < 4; h++) {
            float2 t = ld_sysf2(p + 2*h);
            v[2*h] = t.x; v[2*h+1] = t.y;
        }
    } else {
        float4 a = *(const float4*)p;
        float4 b = *(const float4*)(p + 4);
        v[0]=a.x; v[1]=a.y; v[2]=a.z; v[3]=a.w;
        v[4]=b.x; v[5]=b.y; v[6]=b.z; v[7]=b.w;
    }
}
__device__ __forceinline__ void st8(float* p, const float* v, bool sys) {
    if (sys) {
        st_sysf2(p,     v[0], v[1]);
        st_sysf2(p + 2, v[2], v[3]);
        st_sysf2(p + 4, v[4], v[5]);
        st_sysf2(p + 6, v[6], v[7]);
    } else {
        *(float4*)p       = make_float4(v[0], v[1], v[2], v[3]);
        *(float4*)(p + 4) = make_float4(v[4], v[5], v[6], v[7]);
    }
}

// ---------------- init ----------------
__global__ __launch_bounds__(256)
void k_init(const float* __restrict__ x, float* __restrict__ y,
            int* __restrict__ flags, int* __restrict__ flagT,
            int* __restrict__ flagB, const float* __restrict__ bl,
            float* __restrict__ out)
{
    int idx = blockIdx.x*256 + threadIdx.x;           // < NS
    int b = idx >> 13, px = (idx >> 3) & 1023, c = idx & 7;
    y[idx] = (c < 3) ? x[(size_t)(b*3 + c)*1024 + px] : 0.0f;
    if (idx < 512) { flags[idx] = 0; flagT[idx] = 0; flagB[idx] = 0; }
    if (idx < 640) out[idx] = bl[idx % 10];   // bias pre-init for atomic head
}

// ---------------- prepack ----------------
__global__ __launch_bounds__(256)
void k_prepack(const float* __restrict__ w1, const float* __restrict__ w2,
               const float* __restrict__ w3, _Float16* __restrict__ w2p,
               float* __restrict__ tsum, float* __restrict__ wpk)
{
    int gid = blockIdx.x*256 + threadIdx.x;
    if (gid < 36864) {
        int j    = gid & 7;
        int lane = (gid >> 3) & 63;
        int nt   = (gid >> 9) & 1;
        int ks   = (gid >> 10) & 3;
        int tap  = gid >> 12;            // 0..8
        int oc = nt*32 + (lane & 31);
        int kpos = ks*16 + (lane >> 5)*8 + j;
        int oct = kpos >> 5, q2b = (kpos >> 4) & 1, rr = kpos & 15;
        int ic = oct*32 + (rr & 3) + (q2b << 2) + ((rr >> 2) << 3);  // inv-pi
        w2p[gid] = (_Float16)w2[oc*585 + (1 + ic)*9 + tap];
    }
    if (gid < 576) {
        int oc = gid & 63, combo = gid >> 6;       // 0..8
        int rcase = combo / 3, ccase = combo % 3;
        float s = 0.0f;
        for (int kh = 0; kh < 3; kh++) {
            if ((rcase == 1 && kh == 0) || (rcase == 2 && kh == 2)) continue;
            for (int kw = 0; kw < 3; kw++) {
                if ((ccase == 1 && kw == 0) || (ccase == 2 && kw == 2)) continue;
                s += w2[oc*585 + kh*3 + kw];
            }
        }
        tsum[gid] = s;
    }
    if (gid < 512) wpk[gid] = w1[(gid & 63)*9 + 1 + (gid >> 6)];
    if (gid < 64)  wpk[512 + gid] = w1[gid*9];
    if (gid < 512) wpk[576 + gid] = w3[(gid & 7)*65 + 1 + (gid >> 3)];
    if (gid < 8)   wpk[1088 + gid] = w3[gid*65];
}

// ---------------- the whole ODE solve ----------------
// R12 = R6 exact (best measured, 256us k_ode) + parallelized final head:
// 256 (batch x px-quarter) units over all blocks, wave shfl reduce,
// atomicAdd partials into bias-preinitialized out. Conv2 chain-split (R11)
// reverted: null result, conv2 latency hidden by co-resident block.
__global__ void __launch_bounds__(256, 2)
k_ode(const float* __restrict__ b1, const float* __restrict__ b2,
      const float* __restrict__ b3, const _Float16* __restrict__ w2p,
      const float* __restrict__ tsumg, const float* __restrict__ wpk,
      const float* __restrict__ wl, float* __restrict__ ybuf,
      float* __restrict__ y5buf, float* __restrict__ kb,
      float* __restrict__ part, int* __restrict__ flags,
      int* __restrict__ flagT, int* __restrict__ flagB,
      float* __restrict__ out)
{
    __shared__ __align__(16) unsigned char s_pool[192*ACT_STRIDE]; // 52224
    __shared__ __align__(16) unsigned char s_h2[128*H2_STRIDE];    // 18432
    __shared__ float s_tsum[576];
    __shared__ float s_b2v[64], s_b1v[64], s_w10v[64];
    __shared__ float s_w30v[8], s_b3v[8];
    __shared__ float s_red[40];

    const int tid = threadIdx.x;
    const int nblk = gridDim.x;
    const int lane = tid & 63;
    const int m32 = lane & 31, q2 = lane >> 5;
    const int rp = tid >> 7;          // row-pair for conv2
    const int np = (tid >> 6) & 1;    // oc-half for conv2
    const int wid = tid >> 6;         // wave id
    const bool lz32 = (lane == 32);
    const bool lz31 = (lane == 31);

    if (tid < 64) {
        s_b2v[tid] = b2[tid];
        s_b1v[tid] = b1[tid];
        s_w10v[tid] = wpk[512 + tid];
    }
    if (tid < 8) { s_w30v[tid] = wpk[1088 + tid]; s_b3v[tid] = b3[tid]; }
    for (int i = tid; i < 576; i += 256) s_tsum[i] = tsumg[i];
    __syncthreads();

    // resident conv1 A-frags: lo (k=0..7 live) and hi (k=8..15 live)
    hfrag8 w1lo[2], w1hi[2];
    #pragma unroll
    for (int oct = 0; oct < 2; oct++)
        #pragma unroll
        for (int j = 0; j < 8; j++) {
            _Float16 wv = (_Float16)wpk[j*64 + oct*32 + m32];
            w1lo[oct][j] = q2 ? (_Float16)0.0f : wv;
            w1hi[oct][j] = q2 ? wv : (_Float16)0.0f;
        }
    // resident conv3 A-frags (channel positions permuted by inv-pi)
    hfrag8 w3f[4];
    #pragma unroll
    for (int kst = 0; kst < 4; kst++)
        #pragma unroll
        for (int j = 0; j < 8; j++) {
            int kpos = kst*16 + q2*8 + j;
            int oct = kpos >> 5, q2b = (kpos >> 4) & 1, rr = kpos & 15;
            int ch = oct*32 + (rr & 3) + (q2b << 2) + ((rr >> 2) << 3);
            w3f[kst][j] = (m32 < 8) ? (_Float16)wpk[576 + ch*8 + m32]
                                    : (_Float16)0.0f;
        }

    float t = 0.0f, dt = 0.1f;
    float* ya = ybuf; float* yb = y5buf;
    float* ka = kb;  float* kg = kb + 6*(size_t)NS;

    auto wait_all = [&](int target) {
        for (;;) {
            bool ok = (__hip_atomic_load(&flags[tid], __ATOMIC_RELAXED,
                           __HIP_MEMORY_SCOPE_SYSTEM) >= target)
                   && (__hip_atomic_load(&flags[tid + 256], __ATOMIC_RELAXED,
                           __HIP_MEMORY_SCOPE_SYSTEM) >= target);
            if (__syncthreads_and((int)ok)) break;
            __builtin_amdgcn_s_sleep(2);
        }
    };

    auto eval = [&](const float* src, int nc, const float* cf, float ctv,
                    float* kout, int mode, int gev, float* partp) {
        float dtc = fminf(dt, 1.0f - t);
        float ts  = t + ctv*dtc;

        for (int tile = blockIdx.x; tile < 512; tile += nblk) {
            int b = tile >> 3, rg = tile & 7;

            // ---- z-combine (memory path) ----
            auto zload = [&](int lr) {
                HU pz; pz.v = make_uint4(0u,0u,0u,0u);
                int r = rg*4 - 1 + lr;
                if ((unsigned)lr < 6u && (unsigned)r < 32u) {
                    bool nbr = (lr == 0) | (lr == 5);   // neighbor-written only
                    int px = (r << 5) + m32;
                    size_t pb8 = ((size_t)(b << 10) + px) << 3;
                    float kv[5][8], sv[8];
                    if (nbr) {
                        #pragma unroll
                        for (int j = 0; j < 5; j++) if (j < nc) {
                            const float* kp = (j == 0 ? ka : kb + (size_t)j*NS) + pb8;
                            #pragma unroll
                            for (int h = 0; h < 4; h++) {
                                float2 t2 = ld_sysf2(kp + 2*h);
                                kv[j][2*h] = t2.x; kv[j][2*h+1] = t2.y;
                            }
                        }
                        #pragma unroll
                        for (int h = 0; h < 4; h++) {
                            float2 t2 = ld_sysf2(src + pb8 + 2*h);
                            sv[2*h] = t2.x; sv[2*h+1] = t2.y;
                        }
                    } else {
                        #pragma unroll
                        for (int j = 0; j < 5; j++) if (j < nc) {
                            const float* kp = (j == 0 ? ka : kb + (size_t)j*NS) + pb8;
                            float4 a4 = *(const float4*)kp;
                            float4 b4 = *(const float4*)(kp + 4);
                            kv[j][0]=a4.x; kv[j][1]=a4.y; kv[j][2]=a4.z; kv[j][3]=a4.w;
                            kv[j][4]=b4.x; kv[j][5]=b4.y; kv[j][6]=b4.z; kv[j][7]=b4.w;
                        }
                        float4 a4 = *(const float4*)(src + pb8);
                        float4 b4 = *(const float4*)(src + pb8 + 4);
                        sv[0]=a4.x; sv[1]=a4.y; sv[2]=a4.z; sv[3]=a4.w;
                        sv[4]=b4.x; sv[5]=b4.y; sv[6]=b4.z; sv[7]=b4.w;
                    }
                    float s_[8] = {0,0,0,0,0,0,0,0};
                    #pragma unroll
                    for (int j = 0; j < 5; j++) if (j < nc) {
                        float a = cf[j];
                        #pragma unroll
                        for (int c = 0; c < 8; c++) s_[c] = fmaf(a, kv[j][c], s_[c]);
                    }
                    #pragma unroll
                    for (int c = 0; c < 8; c++)
                        pz.h[c] = (_Float16)(sv[c] + dtc*s_[c]);
                }
                return pz;
            };

            HU pz;
            if (q2 == 0) pz = zload(wid + 1);      // own rows 1..4 (issued pre-spin)
            if (gev > 1 && q2 == 1 && (wid == 0 || wid == 3)) {
                bool need = (wid == 0) ? (rg > 0) : (rg < 7);
                if (need) {
                    const int* fp = (wid == 0) ? &flagB[tile-1] : &flagT[tile+1];
                    while (__hip_atomic_load(fp, __ATOMIC_RELAXED,
                                             __HIP_MEMORY_SCOPE_SYSTEM) < gev-1)
                        __builtin_amdgcn_s_sleep(1);
                }
            }
            if (q2 == 1) pz = zload((wid == 0) ? 0 : ((wid == 3) ? 5 : -1));

            // ---- conv1 via MFMA from registers; act write (pi-permuted) ----
            auto wr_act = [&](int lr, const f32x16& a1, int oct, bool valid) {
                unsigned words[8];
                #pragma unroll
                for (int pr = 0; pr < 8; pr++) {
                    int r0 = 2*pr;
                    int oc0 = oct*32 + (r0 & 3) + 8*(r0 >> 2) + 4*q2;
                    float v0 = valid ? fmaxf(a1[r0]   + ts*s_w10v[oc0]
                                             + s_b1v[oc0],   0.0f) : 0.0f;
                    float v1 = valid ? fmaxf(a1[r0+1] + ts*s_w10v[oc0+1]
                                             + s_b1v[oc0+1], 0.0f) : 0.0f;
                    union { _Float16 h[2]; unsigned u; } pk;
                    pk.h[0] = (_Float16)v0; pk.h[1] = (_Float16)v1;
                    words[pr] = pk.u;
                }
                unsigned char* basep = s_pool + (size_t)(lr*32 + m32)*ACT_STRIDE
                                       + oct*64 + q2*32;
                *(uint4*)basep        = make_uint4(words[0],words[1],words[2],words[3]);
                *(uint4*)(basep + 16) = make_uint4(words[4],words[5],words[6],words[7]);
            };
            {
                f32x16 zz = (f32x16)(0.0f);
                f32x16 c0 = __builtin_amdgcn_mfma_f32_32x32x16_f16(w1lo[0], pz.h, zz, 0,0,0);
                f32x16 c1 = __builtin_amdgcn_mfma_f32_32x32x16_f16(w1lo[1], pz.h, zz, 0,0,0);
                wr_act(wid + 1, c0, 0, true);
                wr_act(wid + 1, c1, 1, true);
                if (wid == 0 || wid == 3) {
                    int lrh = (wid == 0) ? 0 : 5;
                    bool vh = (unsigned)(rg*4 - 1 + lrh) < 32u;
                    f32x16 d0 = __builtin_amdgcn_mfma_f32_32x32x16_f16(w1hi[0], pz.h, zz, 0,0,0);
                    f32x16 d1 = __builtin_amdgcn_mfma_f32_32x32x16_f16(w1hi[1], pz.h, zz, 0,0,0);
                    wr_act(lrh, d0, 0, vh);
                    wr_act(lrh, d1, 1, vh);
                }
            }
            __syncthreads();   // BARRIER-A: act complete

            // ---- conv2: center b128 loads + DPP kw shifts ----
            f32x16 acc2[2];
            acc2[0] = (f32x16)(0.0f);
            acc2[1] = (f32x16)(0.0f);
            {
                const unsigned char* actb = (const unsigned char*)s_pool;
                #pragma unroll 1
                for (int ks = 0; ks < 4; ks++) {
                    HU fc[4], d0[4], d2[4];
                    #pragma unroll
                    for (int l = 0; l < 4; l++) {
                        const unsigned char* p = actb
                            + (size_t)((rp*2 + l)*32 + m32)*ACT_STRIDE
                            + ks*32 + q2*16;
                        fc[l].v = *(const uint4*)p;
                    }
                    #pragma unroll
                    for (int l = 0; l < 4; l++) {
                        #pragma unroll
                        for (int i = 0; i < 4; i++) {
                            unsigned s0 = (unsigned)__builtin_amdgcn_update_dpp(
                                0, (int)fc[l].u[i], 0x138, 0xF, 0xF, true); // wave_shr:1
                            d0[l].u[i] = lz32 ? 0u : s0;
                            unsigned s2 = (unsigned)__builtin_amdgcn_update_dpp(
                                0, (int)fc[l].u[i], 0x130, 0xF, 0xF, true); // wave_shl:1
                            d2[l].u[i] = lz31 ? 0u : s2;
                        }
                    }
                    #pragma unroll
                    for (int kh = 0; kh < 3; kh++) {
                        #pragma unroll
                        for (int kw = 0; kw < 3; kw++) {
                            int tap = kh*3 + kw;
                            hfrag8 aw = *(const hfrag8*)
                                (w2p + (size_t)((tap*4 + ks)*2 + np)*512 + lane*8);
                            #pragma unroll
                            for (int ri = 0; ri < 2; ri++) {
                                int l = ri + kh;
                                hfrag8 bf = (kw == 0) ? d0[l].h
                                          : ((kw == 1) ? fc[l].h : d2[l].h);
                                acc2[ri] = __builtin_amdgcn_mfma_f32_32x32x16_f16(
                                    aw, bf, acc2[ri], 0, 0, 0);
                            }
                        }
                    }
                }
            }

            // ---- conv2 epilogue -> h2 (pi-permuted px-major fp16) ----
            {
                int ccase = (m32 == 0) ? 1 : ((m32 == 31) ? 2 : 0);
                #pragma unroll
                for (int ri = 0; ri < 2; ri++) {
                    int pg = rp*2 + ri;
                    int r_out = rg*4 + pg;
                    int rcase = (r_out == 0) ? 1 : ((r_out == 31) ? 2 : 0);
                    const float* tsb = &s_tsum[(rcase*3 + ccase)*64];
                    int px = pg*32 + m32;
                    unsigned words[8];
                    #pragma unroll
                    for (int pr = 0; pr < 8; pr++) {
                        int r0 = 2*pr;
                        int oc0 = np*32 + (r0 & 3) + 8*(r0 >> 2) + 4*q2;
                        float v0 = fmaxf(acc2[ri][r0]   + ts*tsb[oc0]
                                         + s_b2v[oc0],   0.0f);
                        float v1 = fmaxf(acc2[ri][r0+1] + ts*tsb[oc0+1]
                                         + s_b2v[oc0+1], 0.0f);
                        union { _Float16 h[2]; unsigned u; } pk;
                        pk.h[0] = (_Float16)v0; pk.h[1] = (_Float16)v1;
                        words[pr] = pk.u;
                    }
                    unsigned char* basep = s_h2 + (size_t)px*H2_STRIDE
                                           + np*64 + q2*32;
                    *(uint4*)basep        = make_uint4(words[0],words[1],words[2],words[3]);
                    *(uint4*)(basep + 16) = make_uint4(words[4],words[5],words[6],words[7]);
                }
            }
            __syncthreads();   // BARRIER-B: h2 complete

            // ---- conv3 via MFMA + mode epilogues ----
            float ls = 0.0f;
            {
                f32x16 a3a = (f32x16)(0.0f);
                #pragma unroll
                for (int kst = 0; kst < 4; kst++) {
                    HU f;
                    const unsigned char* p = s_h2
                        + (size_t)(wid*32 + m32)*H2_STRIDE + kst*32 + q2*16;
                    f.v = *(const uint4*)p;
                    a3a = __builtin_amdgcn_mfma_f32_32x32x16_f16(
                        w3f[kst], f.h, a3a, 0, 0, 0);
                }
                float a3[8];
                #pragma unroll
                for (int r = 0; r < 4; r++) {
                    float own = a3a[r];
                    float oth = __shfl(own, lane ^ 32, 64);
                    a3[r]     = q2 ? oth : own;
                    a3[4 + r] = q2 ? own : oth;
                }
                if (q2 == 0) {
                    #pragma unroll
                    for (int c = 0; c < 8; c++)
                        a3[c] += fmaf(ts, s_w30v[c], s_b3v[c]);
                    bool edge = (wid == 0) | (wid == 3);
                    int px = rg*128 + wid*32 + m32;
                    size_t pb8 = ((size_t)(b << 10) + px) << 3;
                    st8(kout + pb8, a3, edge);
                    if (mode == 1) {
                        float kv1[8], kv3[8], kv4[8], kv5[8], yv[8], r8[8];
                        ld8(ka + pb8, kv1, false);
                        ld8(kb + 2*(size_t)NS + pb8, kv3, false);
                        ld8(kb + 3*(size_t)NS + pb8, kv4, false);
                        ld8(kb + 4*(size_t)NS + pb8, kv5, false);
                        ld8(ya + pb8, yv, false);
                        #pragma unroll
                        for (int c = 0; c < 8; c++)
                            r8[c] = yv[c] + dtc*(B1c*kv1[c] + B3c*kv3[c]
                                    + B4c*kv4[c] + B5c*kv5[c] + B6c*a3[c]);
                        st8(yb + pb8, r8, edge);
                    } else if (mode == 2) {
                        float kv1[8], kv3[8], kv4[8], kv5[8], kv6[8], yv[8], y5v[8];
                        ld8(ka + pb8, kv1, false);
                        ld8(kb + 2*(size_t)NS + pb8, kv3, false);
                        ld8(kb + 3*(size_t)NS + pb8, kv4, false);
                        ld8(kb + 4*(size_t)NS + pb8, kv5, false);
                        ld8(kb + 5*(size_t)NS + pb8, kv6, false);
                        ld8(ya + pb8, yv, false);
                        ld8(yb + pb8, y5v, false);
                        #pragma unroll
                        for (int c = 0; c < 8; c++) {
                            float e = dtc*(E1c*kv1[c] + E3c*kv3[c] + E4c*kv4[c]
                                           + E5c*kv5[c] + E6c*kv6[c] + E7c*a3[c]);
                            float tol = ATOL + RTOL*fmaxf(fabsf(yv[c]), fabsf(y5v[c]));
                            float rr = e / tol;
                            ls += rr*rr;
                        }
                    }
                }
            }
            // per-wave drain then early halo release (no block barrier)
            asm volatile("s_waitcnt vmcnt(0)" ::: "memory");
            if (lane == 0 && wid == 0)
                __hip_atomic_store(&flagT[tile], gev, __ATOMIC_RELAXED,
                                   __HIP_MEMORY_SCOPE_SYSTEM);
            if (lane == 0 && wid == 3)
                __hip_atomic_store(&flagB[tile], gev, __ATOMIC_RELAXED,
                                   __HIP_MEMORY_SCOPE_SYSTEM);
            if (mode == 2) {
                float v = ls;
                #pragma unroll
                for (int off = 1; off < 64; off <<= 1)
                    v += __shfl_xor(v, off, 64);
                if (lane == 0) s_red[wid] = v;
                __syncthreads();
                if (tid == 0) {
                    st_sysf(&partp[tile],
                            s_red[0] + s_red[1] + s_red[2] + s_red[3]);
                    asm volatile("s_waitcnt vmcnt(0)" ::: "memory");
                    __hip_atomic_store(&flags[tile], gev, __ATOMIC_RELAXED,
                                       __HIP_MEMORY_SCOPE_SYSTEM);
                }
            }
        }
    };

    int gev = 1;
    eval(ya, 0, g_cf[5], 0.0f, ka, 0, gev, part);   // k1 = f(t0, y0)
    gev++;

    for (int st = 0; st < 24; st++) {
        if (t >= 1.0f - 1e-7f) break;
        float* partp = part + (size_t)(st & 1)*512;
        for (int e = 0; e < 6; e++) {
            int nc = (e < 5) ? e + 1 : 0;
            const float* src = (e == 5) ? yb : ya;
            float* kout = (e < 5) ? kb + (size_t)(e + 1)*NS : kg;
            int mode = (e == 4) ? 1 : ((e == 5) ? 2 : 0);
            eval(src, nc, g_cf[e], g_ct[e], kout, mode, gev, partp);
            gev++;
        }
        wait_all(gev - 1);   // all tiles finished the err eval (partials at L3)
        float v = ld_sysf(&partp[tid]) + ld_sysf(&partp[tid + 256]);
        #pragma unroll
        for (int off = 1; off < 64; off <<= 1)
            v += __shfl_xor(v, off, 64);
        if (lane == 0) s_red[wid] = v;
        __syncthreads();
        float red0 = s_red[0] + s_red[1] + s_red[2] + s_red[3];
        float err_norm = sqrtf(red0 / (float)NS);
        float dtc = fminf(dt, 1.0f - t);
        bool adv = (err_norm <= 1.0f);
        if (adv) {
            t = t + dtc;
            float* tmp = ya; ya = yb; yb = tmp;   // y <- y5
            tmp = ka; ka = kg; kg = tmp;          // k1 <- k7 (FSAL)
        }
        float safe = fmaxf(err_norm, 1e-10f);
        float factor = fminf(fmaxf(0.9f*powf(safe, -0.2f), 0.2f), 10.0f);
        dt = dtc*factor;
    }

    // flush private interior rows of final y to L3, then publish + wait
    for (int tile = blockIdx.x; tile < 512; tile += nblk) {
        int b = tile >> 3, rg = tile & 7;
        if (tid < 128) {
            int lrow = tid >> 5;
            if (lrow == 1 || lrow == 2) {
                int px = rg*128 + tid;
                float* yp = ya + (((size_t)(b << 10) + px) << 3);
                float4 v0 = *(const float4*)yp;
                float4 v1 = *(const float4*)(yp + 4);
                st_sysf2(yp,     v0.x, v0.y);
                st_sysf2(yp + 2, v0.z, v0.w);
                st_sysf2(yp + 4, v1.x, v1.y);
                st_sysf2(yp + 6, v1.z, v1.w);
            }
        }
    }
    __syncthreads();
    for (int tile = blockIdx.x; tile < 512; tile += nblk)
        if (tid == 0)
            __hip_atomic_store(&flags[tile], gev, __ATOMIC_RELAXED,
                               __HIP_MEMORY_SCOPE_SYSTEM);
    wait_all(gev);

    // final linear head: 256 units (bh x px-quarter), atomic partials
    for (int hb = blockIdx.x; hb < 256; hb += nblk) {
        int bh = hb >> 2, q = hb & 3;
        int px = q*256 + tid;
        const float* yp = ya + (((size_t)(bh << 10) + px) << 3);
        float acc[10];
        #pragma unroll
        for (int m = 0; m < 10; m++) acc[m] = 0.0f;
        float yv[8];
        #pragma unroll
        for (int h = 0; h < 4; h++) {
            float2 v = ld_sysf2(yp + 2*h);
            yv[2*h] = v.x; yv[2*h+1] = v.y;
        }
        #pragma unroll
        for (int c = 0; c < 8; c++) {
            float v = yv[c];
            #pragma unroll
            for (int m = 0; m < 10; m++)
                acc[m] = fmaf(v, wl[(size_t)m*8192 + (c << 10) + px], acc[m]);
        }
        #pragma unroll
        for (int m = 0; m < 10; m++) {
            float v = acc[m];
            #pragma unroll
            for (int off = 1; off < 64; off <<= 1)
                v += __shfl_xor(v, off, 64);
            acc[m] = v;
        }
        if (lane == 0) {
            #pragma unroll
            for (int m = 0; m < 10; m++) s_red[wid*10 + m] = acc[m];
        }
        __syncthreads();
        if (tid < 10) {
            float v = s_red[tid] + s_red[10 + tid]
                    + s_red[20 + tid] + s_red[30 + tid];
            atomicAdd(&out[bh*10 + tid], v);
        }
        __syncthreads();
    }
}

// ---------------- host ----------------
extern "C" void kernel_launch(void* const* d_in, const int* in_sizes, int n_in,
                              void* d_out, int out_size, void* d_ws, size_t ws_size,
                              hipStream_t stream)
{
    const float* x  = (const float*)d_in[0];
    const float* w1 = (const float*)d_in[1];
    const float* b1 = (const float*)d_in[2];
    const float* w2 = (const float*)d_in[3];
    const float* b2 = (const float*)d_in[4];
    const float* w3 = (const float*)d_in[5];
    const float* b3 = (const float*)d_in[6];
    const float* wl = (const float*)d_in[7];
    const float* bl = (const float*)d_in[8];
    float* out = (float*)d_out;

    float* F = (float*)d_ws;
    float* part = F + OFF_PART;
    int*   flags = (int*)(F + OFF_FLAG);
    float* tsum = F + OFF_TSUM;
    _Float16* w2p = (_Float16*)(F + OFF_W2P);
    float* y    = F + OFF_Y;
    float* y5   = F + OFF_Y5;
    float* kbp  = F + OFF_K;
    float* wpk  = F + OFF_WPK;
    int*   flagT = (int*)(F + OFF_FT);
    int*   flagB = (int*)(F + OFF_FB);

    k_init<<<NS/256, 256, 0, stream>>>(x, y, flags, flagT, flagB, bl, out);
    k_prepack<<<144, 256, 0, stream>>>(w1, w2, w3, w2p, tsum, wpk);

    int maxb = 0;
    if (hipOccupancyMaxActiveBlocksPerMultiprocessor(&maxb,
            reinterpret_cast<const void*>(k_ode), 256, 0) != hipSuccess || maxb < 1)
        maxb = 1;
    int cus = 256;
    {
        int dev = 0;
        hipGetDevice(&dev);
        hipDeviceProp_t prop;
        if (hipGetDeviceProperties(&prop, dev) == hipSuccess && prop.multiProcessorCount > 0)
            cus = prop.multiProcessorCount;
    }
    long cap = (long)maxb * (long)cus;
    int gridn = (int)((cap < 512) ? cap : 512);
    if (gridn < 16) gridn = 16;

    k_ode<<<gridn, 256, 0, stream>>>(b1, b2, b3, w2p, tsum, wpk, wl,
                                     y, y5, kbp, part, flags, flagT, flagB, out);
}